// Round 4
// baseline (2090.044 us; speedup 1.0000x reference)
//
#include <hip/hip_runtime.h>
#include <hip/hip_bf16.h>

#define NEG 0.2f

__device__ __forceinline__ unsigned int fkey(float f){
  unsigned int b = __float_as_uint(f);
  return (b & 0x80000000u) ? ~b : (b | 0x80000000u);
}
__device__ __forceinline__ float fdec(unsigned int k){
  unsigned int b = (k & 0x80000000u) ? (k & 0x7FFFFFFFu) : ~k;
  return __uint_as_float(b);
}

// ---------------- Layer 1 GEMM: fs = h@Ws, fd = h@Wd  (N x 128 @ 128 x 128) ----
#define GN1 16
__global__ __launch_bounds__(128)
void k_gemm1(const float* __restrict__ h, const float* __restrict__ Ws,
             const float* __restrict__ Wd, float* __restrict__ fs,
             float* __restrict__ fd, int n){
  __shared__ float hs[GN1][128];
  int col = threadIdx.x;            // 0..127
  int node0 = blockIdx.x * GN1;
  for (int i = 0; i < GN1; ++i){
    int nd = node0 + i;
    hs[i][col] = (nd < n) ? h[(size_t)nd*128 + col] : 0.f;
  }
  __syncthreads();
  float accs[GN1], accd[GN1];
  #pragma unroll
  for (int i = 0; i < GN1; ++i){ accs[i]=0.f; accd[i]=0.f; }
  for (int k = 0; k < 128; ++k){
    float ws = Ws[k*128 + col];
    float wd = Wd[k*128 + col];
    #pragma unroll
    for (int i = 0; i < GN1; ++i){
      accs[i] = fmaf(hs[i][k], ws, accs[i]);
      accd[i] = fmaf(hs[i][k], wd, accd[i]);
    }
  }
  for (int i = 0; i < GN1; ++i){
    int nd = node0 + i;
    if (nd < n){
      fs[(size_t)nd*128 + col] = accs[i];
      fd[(size_t)nd*128 + col] = accd[i];
    }
  }
}

// ---------------- Layer 1 edge scores: wave per edge, float2 per lane ---------
__global__ __launch_bounds__(256)
void k_score1(const float* __restrict__ fs, const float* __restrict__ fd,
              const int* __restrict__ src, const int* __restrict__ dst,
              const float* __restrict__ a1,
              float* __restrict__ score, unsigned int* __restrict__ mkey, int ne){
  int e = (int)((blockIdx.x * 256u + threadIdx.x) >> 6);
  int lane = threadIdx.x & 63;
  if (e >= ne) return;
  int s = src[e], d = dst[e];
  float2 va = ((const float2*)fs)[(size_t)s*64 + lane];  // dims 2*lane, 2*lane+1
  float2 vb = ((const float2*)fd)[(size_t)d*64 + lane];
  float x0 = va.x + vb.x, x1 = va.y + vb.y;
  x0 = x0 > 0.f ? x0 : NEG * x0;
  x1 = x1 > 0.f ? x1 : NEG * x1;
  float2 aw = ((const float2*)a1)[lane];                 // a1 flat [h*64+d]
  float p = x0*aw.x + x1*aw.y;
  // lanes 0..31 hold head0 dims, 32..63 head1. Reduce within each 32-half.
  #pragma unroll
  for (int off = 16; off >= 1; off >>= 1) p += __shfl_xor(p, off, 64);
  int h = lane >> 5;
  if ((lane & 31) == 0){
    score[(size_t)e*2 + h] = p;
    atomicMax(&mkey[(size_t)d*2 + h], fkey(p));
  }
}

// ---------------- Layer 1 exp + denom ----------------------------------------
__global__ __launch_bounds__(256)
void k_exp1(float* __restrict__ score, const int* __restrict__ dst,
            const unsigned int* __restrict__ mkey, float* __restrict__ denom, int ne){
  int i = blockIdx.x * 256 + threadIdx.x;
  if (i >= ne*2) return;
  int e = i >> 1, h = i & 1;
  int d = dst[e];
  float m = fdec(mkey[(size_t)d*2 + h]);
  float ex = __expf(score[i] - m);
  score[i] = ex;                       // overwrite score with exp value
  atomicAdd(&denom[(size_t)d*2 + h], ex);
}

// ---------------- Layer 1 aggregate: wave per edge, atomicAdd ----------------
__global__ __launch_bounds__(256)
void k_agg1(const float* __restrict__ fs, const float* __restrict__ score,
            const float* __restrict__ denom, const int* __restrict__ src,
            const int* __restrict__ dst, float* __restrict__ out, int ne){
  int e = (int)((blockIdx.x * 256u + threadIdx.x) >> 6);
  int lane = threadIdx.x & 63;
  if (e >= ne) return;
  int s = src[e], d = dst[e];
  int h = lane >> 5;
  float alpha = score[(size_t)e*2 + h] / denom[(size_t)d*2 + h];
  float2 v = ((const float2*)fs)[(size_t)s*64 + lane];
  atomicAdd(&out[(size_t)d*128 + 2*lane    ], alpha * v.x);
  atomicAdd(&out[(size_t)d*128 + 2*lane + 1], alpha * v.y);
}

// ---------------- ELU in place -----------------------------------------------
__global__ __launch_bounds__(256)
void k_elu(float* __restrict__ x, int total){
  int i = blockIdx.x * 256 + threadIdx.x;
  if (i < total){
    float v = x[i];
    x[i] = v > 0.f ? v : (__expf(v) - 1.f);
  }
}

// ---------------- Layer 2 GEMM: fs2/fd2/res = h1 @ {W2s,W2d,Wr} (128 -> 16) --
__global__ __launch_bounds__(256)
void k_gemm2(const float* __restrict__ h1, const float* __restrict__ Ws,
             const float* __restrict__ Wd, const float* __restrict__ Wr,
             float* __restrict__ fs2, float* __restrict__ fd2,
             float* __restrict__ res, int n){
  __shared__ float hs[16][129];
  __shared__ float w[3][128][16];
  int tid = threadIdx.x;
  for (int i = tid; i < 2048; i += 256){
    int k = i >> 4, j = i & 15;
    w[0][k][j] = Ws[i]; w[1][k][j] = Wd[i]; w[2][k][j] = Wr[i];
  }
  int node0 = blockIdx.x * 16;
  for (int i = tid; i < 2048; i += 256){
    int r = i >> 7, c = i & 127;
    int nd = node0 + r;
    hs[r][c] = (nd < n) ? h1[(size_t)nd*128 + c] : 0.f;
  }
  __syncthreads();
  int j = tid & 15, ni = tid >> 4;
  float as = 0.f, ad = 0.f, ar = 0.f;
  for (int k = 0; k < 128; ++k){
    float hv = hs[ni][k];
    as = fmaf(hv, w[0][k][j], as);
    ad = fmaf(hv, w[1][k][j], ad);
    ar = fmaf(hv, w[2][k][j], ar);
  }
  int nd = node0 + ni;
  if (nd < n){
    fs2[(size_t)nd*16 + j] = as;
    fd2[(size_t)nd*16 + j] = ad;
    res[(size_t)nd*16 + j] = ar;
  }
}

// ---------------- Layer 2 scores: 16 lanes per edge --------------------------
__global__ __launch_bounds__(256)
void k_score2(const float* __restrict__ fs2, const float* __restrict__ fd2,
              const int* __restrict__ src, const int* __restrict__ dst,
              const float* __restrict__ a2,
              float* __restrict__ score, unsigned int* __restrict__ mkey, int ne){
  int e = (int)((blockIdx.x * 256u + threadIdx.x) >> 4);
  int j = threadIdx.x & 15;
  if (e >= ne) return;
  int s = src[e], d = dst[e];
  float x = fs2[(size_t)s*16 + j] + fd2[(size_t)d*16 + j];
  x = x > 0.f ? x : NEG * x;
  float p = x * a2[j];
  #pragma unroll
  for (int off = 8; off >= 1; off >>= 1) p += __shfl_xor(p, off, 64);
  if (j == 0){
    score[e] = p;
    atomicMax(&mkey[d], fkey(p));
  }
}

__global__ __launch_bounds__(256)
void k_exp2(float* __restrict__ score, const int* __restrict__ dst,
            const unsigned int* __restrict__ mkey, float* __restrict__ denom, int ne){
  int e = blockIdx.x * 256 + threadIdx.x;
  if (e >= ne) return;
  int d = dst[e];
  float m = fdec(mkey[d]);
  float ex = __expf(score[e] - m);
  score[e] = ex;
  atomicAdd(&denom[d], ex);
}

__global__ __launch_bounds__(256)
void k_agg2(const float* __restrict__ fs2, const float* __restrict__ score,
            const float* __restrict__ denom, const int* __restrict__ src,
            const int* __restrict__ dst, float* __restrict__ h2, int ne){
  int e = (int)((blockIdx.x * 256u + threadIdx.x) >> 4);
  int j = threadIdx.x & 15;
  if (e >= ne) return;
  int s = src[e], d = dst[e];
  float alpha = score[e] / denom[d];
  atomicAdd(&h2[(size_t)d*16 + j], alpha * fs2[(size_t)s*16 + j]);
}

// ---------------- Final: logits = h2 + res -----------------------------------
__global__ __launch_bounds__(256)
void k_final(const float* __restrict__ h2, const float* __restrict__ res,
             float* __restrict__ out, int total){
  int i = blockIdx.x * 256 + threadIdx.x;
  if (i < total) out[i] = h2[i] + res[i];
}

extern "C" void kernel_launch(void* const* d_in, const int* in_sizes, int n_in,
                              void* d_out, int out_size, void* d_ws, size_t ws_size,
                              hipStream_t stream) {
  const float* h    = (const float*)d_in[0];
  const int*   src  = (const int*)  d_in[1];
  const int*   dst  = (const int*)  d_in[2];
  const float* W1s  = (const float*)d_in[3];
  const float* W1d  = (const float*)d_in[4];
  const float* a1   = (const float*)d_in[5];
  const float* W2s  = (const float*)d_in[6];
  const float* W2d  = (const float*)d_in[7];
  const float* a2   = (const float*)d_in[8];
  const float* Wres = (const float*)d_in[9];
  float* out = (float*)d_out;

  const int n  = in_sizes[0] / 128;   // 50000
  const int ne = in_sizes[1];         // 1600000

  // ---- workspace layout (floats) ----
  float* ws = (float*)d_ws;
  float* fs1 = ws;                                  // n*128
  float* fd1 = fs1 + (size_t)n*128;                 // n*128 (reused as out1/h1)
  float* sc1 = fd1 + (size_t)n*128;                 // ne*2  (score -> exp)
  unsigned int* m1 = (unsigned int*)(sc1 + (size_t)ne*2);   // n*2
  float* de1 = (float*)(m1 + (size_t)n*2);          // n*2
  float* fs2 = de1 + (size_t)n*2;                   // n*16
  float* fd2 = fs2 + (size_t)n*16;                  // n*16
  float* res = fd2 + (size_t)n*16;                  // n*16
  float* sc2 = res + (size_t)n*16;                  // ne
  unsigned int* m2 = (unsigned int*)(sc2 + (size_t)ne);     // n
  float* de2 = (float*)(m2 + (size_t)n);            // n
  float* h2  = de2 + (size_t)n;                     // n*16

  // ---- zero-init accumulators (0x00000000 is the fkey identity for max) ----
  hipMemsetAsync(m1,  0, (size_t)n*2*4,  stream);
  hipMemsetAsync(de1, 0, (size_t)n*2*4,  stream);
  hipMemsetAsync(m2,  0, (size_t)n*4,    stream);
  hipMemsetAsync(de2, 0, (size_t)n*4,    stream);
  hipMemsetAsync(h2,  0, (size_t)n*16*4, stream);

  // ---- layer 1 ----
  k_gemm1<<<(n + GN1 - 1)/GN1, 128, 0, stream>>>(h, W1s, W1d, fs1, fd1, n);
  k_score1<<<(ne + 3)/4, 256, 0, stream>>>(fs1, fd1, src, dst, a1, sc1, m1, ne);
  // fd1 is dead now; reuse as out1 (zeroed)
  hipMemsetAsync(fd1, 0, (size_t)n*128*4, stream);
  k_exp1<<<(ne*2 + 255)/256, 256, 0, stream>>>(sc1, dst, m1, de1, ne);
  k_agg1<<<(ne + 3)/4, 256, 0, stream>>>(fs1, sc1, de1, src, dst, fd1, ne);
  k_elu<<<((size_t)n*128 + 255)/256, 256, 0, stream>>>(fd1, n*128);

  // ---- layer 2 ----
  k_gemm2<<<(n + 15)/16, 256, 0, stream>>>(fd1, W2s, W2d, Wres, fs2, fd2, res, n);
  k_score2<<<(ne + 15)/16, 256, 0, stream>>>(fs2, fd2, src, dst, a2, sc2, m2, ne);
  k_exp2<<<(ne + 255)/256, 256, 0, stream>>>(sc2, dst, m2, de2, ne);
  k_agg2<<<(ne + 15)/16, 256, 0, stream>>>(fs2, sc2, de2, src, dst, h2, ne);
  k_final<<<((size_t)n*16 + 255)/256, 256, 0, stream>>>(h2, res, out, n*16);
}

// Round 5
// 558.792 us; speedup vs baseline: 3.7403x; 3.7403x over previous
//
#include <hip/hip_runtime.h>
#include <hip/hip_bf16.h>

#define NEG 0.2f
#define FNEG_MAX -3.402823466e38f

// ============ CSR build ============
__global__ __launch_bounds__(256)
void k_count(const int* __restrict__ dst, int* __restrict__ deg, int ne){
  int e = blockIdx.x*256 + threadIdx.x;
  if (e < ne) atomicAdd(&deg[dst[e]], 1);
}

#define SCB 512
__global__ __launch_bounds__(SCB)
void k_scan1(const int* __restrict__ deg, int* __restrict__ off,
             int* __restrict__ bsum, int n){
  __shared__ int lds[SCB];
  int t = threadIdx.x, i = blockIdx.x*SCB + t;
  int x = (i < n) ? deg[i] : 0;
  lds[t] = x; __syncthreads();
  for (int s = 1; s < SCB; s <<= 1){
    int v = (t >= s) ? lds[t-s] : 0;
    __syncthreads();
    lds[t] += v;
    __syncthreads();
  }
  if (i < n) off[i] = lds[t] - x;            // exclusive
  if (t == SCB-1) bsum[blockIdx.x] = lds[t]; // block total
}

__global__ void k_scan2(int* __restrict__ bsum, int nblk){
  if (threadIdx.x == 0 && blockIdx.x == 0){
    int acc = 0;
    for (int b = 0; b < nblk; ++b){ int v = bsum[b]; bsum[b] = acc; acc += v; }
  }
}

__global__ __launch_bounds__(SCB)
void k_scan3(int* __restrict__ off, const int* __restrict__ bsum, int n, int ne){
  int i = blockIdx.x*SCB + threadIdx.x;
  if (i < n) off[i] += bsum[blockIdx.x];
  if (i == 0) off[n] = ne;
}

__global__ __launch_bounds__(256)
void k_scatter(const int* __restrict__ src, const int* __restrict__ dst,
               const int* __restrict__ off, int* __restrict__ cur,
               int* __restrict__ csr_src, int ne){
  int e = blockIdx.x*256 + threadIdx.x;
  if (e >= ne) return;
  int d = dst[e];
  int pos = off[d] + atomicAdd(&cur[d], 1);
  csr_src[pos] = src[e];
}

// ============ Layer 1 GEMM: fs = h@Ws, fd = h@Wd  (N x 128 @ 128 x 128) ======
#define GN1 16
__global__ __launch_bounds__(128)
void k_gemm1(const float* __restrict__ h, const float* __restrict__ Ws,
             const float* __restrict__ Wd, float* __restrict__ fs,
             float* __restrict__ fd, int n){
  __shared__ float hs[GN1][128];
  int col = threadIdx.x;
  int node0 = blockIdx.x * GN1;
  for (int i = 0; i < GN1; ++i){
    int nd = node0 + i;
    hs[i][col] = (nd < n) ? h[(size_t)nd*128 + col] : 0.f;
  }
  __syncthreads();
  float accs[GN1], accd[GN1];
  #pragma unroll
  for (int i = 0; i < GN1; ++i){ accs[i]=0.f; accd[i]=0.f; }
  for (int k = 0; k < 128; ++k){
    float ws = Ws[k*128 + col];
    float wd = Wd[k*128 + col];
    #pragma unroll
    for (int i = 0; i < GN1; ++i){
      accs[i] = fmaf(hs[i][k], ws, accs[i]);
      accd[i] = fmaf(hs[i][k], wd, accd[i]);
    }
  }
  for (int i = 0; i < GN1; ++i){
    int nd = node0 + i;
    if (nd < n){
      fs[(size_t)nd*128 + col] = accs[i];
      fd[(size_t)nd*128 + col] = accd[i];
    }
  }
}

// ============ Layer 1 fused: per-node online-softmax aggregate + ELU =========
// One wave per node. Lane l holds dims 2l,2l+1 (head = lane>>5).
// NOTE: `fdv_` and `out` alias (fd1 reused as h1 output): each wave reads only
// its own node's fd row before writing that same row; rows are wave-private.
__global__ __launch_bounds__(256)
void k_l1_node(const float* __restrict__ fs, const float* fdv_,
               const int* __restrict__ off, const int* __restrict__ csr,
               const float* __restrict__ a1, float* out, int n){
  int wid  = (int)((blockIdx.x*256u + threadIdx.x) >> 6);
  int lane = threadIdx.x & 63;
  if (wid >= n) return;
  int d = wid;
  int e0 = off[d], e1 = off[d+1];
  float2 fdv = ((const float2*)fdv_)[(size_t)d*64 + lane];
  float2 aw  = ((const float2*)a1)[lane];
  float m = FNEG_MAX, den = 0.f;
  float ax = 0.f, ay = 0.f;
  for (int i = e0; i < e1; ++i){
    int s = csr[i];
    float2 v = ((const float2*)fs)[(size_t)s*64 + lane];
    float x0 = v.x + fdv.x, x1 = v.y + fdv.y;
    x0 = x0 > 0.f ? x0 : NEG*x0;
    x1 = x1 > 0.f ? x1 : NEG*x1;
    float p = x0*aw.x + x1*aw.y;
    #pragma unroll
    for (int o = 16; o >= 1; o >>= 1) p += __shfl_xor(p, o, 64);
    // online softmax update (branchless rescale)
    float nm    = fmaxf(m, p);
    float scale = __expf(m - nm);
    float w     = __expf(p - nm);
    den = den*scale + w;
    ax  = ax*scale + w*v.x;
    ay  = ay*scale + w*v.y;
    m = nm;
  }
  float inv = (den > 0.f) ? 1.f/den : 0.f;
  float y0 = ax*inv, y1 = ay*inv;
  y0 = y0 > 0.f ? y0 : __expf(y0) - 1.f;   // ELU fused
  y1 = y1 > 0.f ? y1 : __expf(y1) - 1.f;
  ((float2*)out)[(size_t)d*64 + lane] = make_float2(y0, y1);
}

// ============ Layer 2 GEMM: fs2/fd2/res = h1 @ {W2s,W2d,Wr} (128 -> 16) ======
__global__ __launch_bounds__(256)
void k_gemm2(const float* __restrict__ h1, const float* __restrict__ Ws,
             const float* __restrict__ Wd, const float* __restrict__ Wr,
             float* __restrict__ fs2, float* __restrict__ fd2,
             float* __restrict__ res, int n){
  __shared__ float hs[16][129];
  __shared__ float w[3][128][16];
  int tid = threadIdx.x;
  for (int i = tid; i < 2048; i += 256){
    int k = i >> 4, j = i & 15;
    w[0][k][j] = Ws[i]; w[1][k][j] = Wd[i]; w[2][k][j] = Wr[i];
  }
  int node0 = blockIdx.x * 16;
  for (int i = tid; i < 2048; i += 256){
    int r = i >> 7, c = i & 127;
    int nd = node0 + r;
    hs[r][c] = (nd < n) ? h1[(size_t)nd*128 + c] : 0.f;
  }
  __syncthreads();
  int j = tid & 15, ni = tid >> 4;
  float as = 0.f, ad = 0.f, ar = 0.f;
  for (int k = 0; k < 128; ++k){
    float hv = hs[ni][k];
    as = fmaf(hv, w[0][k][j], as);
    ad = fmaf(hv, w[1][k][j], ad);
    ar = fmaf(hv, w[2][k][j], ar);
  }
  int nd = node0 + ni;
  if (nd < n){
    fs2[(size_t)nd*16 + j] = as;
    fd2[(size_t)nd*16 + j] = ad;
    res[(size_t)nd*16 + j] = ar;
  }
}

// ============ Layer 2 fused: per-node online softmax + residual -> d_out =====
// One wave per node; 4 groups of 16 lanes process edges strided, then merge.
__global__ __launch_bounds__(256)
void k_l2_node(const float* __restrict__ fs2, const float* __restrict__ fd2,
               const float* __restrict__ resd, const int* __restrict__ off,
               const int* __restrict__ csr, const float* __restrict__ a2,
               float* __restrict__ outp, int n){
  int wid  = (int)((blockIdx.x*256u + threadIdx.x) >> 6);
  int lane = threadIdx.x & 63;
  if (wid >= n) return;
  int d = wid;
  int g = lane >> 4, j = lane & 15;
  int e0 = off[d], e1 = off[d+1];
  float fdv = fd2[(size_t)d*16 + j];
  float aw  = a2[j];
  float m = FNEG_MAX, den = 0.f, acc = 0.f;
  for (int i = e0 + g; i < e1; i += 4){
    int s = csr[i];
    float v = fs2[(size_t)s*16 + j];
    float x = v + fdv; x = x > 0.f ? x : NEG*x;
    float p = x * aw;
    #pragma unroll
    for (int o = 8; o >= 1; o >>= 1) p += __shfl_xor(p, o, 64);
    float nm = fmaxf(m, p);
    float sc = __expf(m - nm);
    float w  = __expf(p - nm);
    den = den*sc + w;
    acc = acc*sc + w*v;
    m = nm;
  }
  // merge the 4 groups' (m, den, acc): butterfly xor 16 then 32
  #pragma unroll
  for (int o = 16; o <= 32; o <<= 1){
    float om   = __shfl_xor(m,   o, 64);
    float oden = __shfl_xor(den, o, 64);
    float oacc = __shfl_xor(acc, o, 64);
    float nm = fmaxf(m, om);
    float s1 = __expf(m - nm);    // -FLT_MAX sentinel: exp underflows to 0 safely
    float s2 = __expf(om - nm);
    den = den*s1 + oden*s2;
    acc = acc*s1 + oacc*s2;
    m = nm;
  }
  if (g == 0){
    float inv = (den > 0.f) ? 1.f/den : 0.f;
    outp[(size_t)d*16 + j] = acc*inv + resd[(size_t)d*16 + j];
  }
}

extern "C" void kernel_launch(void* const* d_in, const int* in_sizes, int n_in,
                              void* d_out, int out_size, void* d_ws, size_t ws_size,
                              hipStream_t stream) {
  const float* h    = (const float*)d_in[0];
  const int*   src  = (const int*)  d_in[1];
  const int*   dst  = (const int*)  d_in[2];
  const float* W1s  = (const float*)d_in[3];
  const float* W1d  = (const float*)d_in[4];
  const float* a1   = (const float*)d_in[5];
  const float* W2s  = (const float*)d_in[6];
  const float* W2d  = (const float*)d_in[7];
  const float* a2   = (const float*)d_in[8];
  const float* Wres = (const float*)d_in[9];
  float* out = (float*)d_out;

  const int n  = in_sizes[0] / 128;   // 50000
  const int ne = in_sizes[1];         // 1600000

  // ---- workspace layout ----
  float* ws  = (float*)d_ws;
  float* fs1 = ws;                         // n*128
  float* fd1 = fs1 + (size_t)n*128;        // n*128 (becomes h1 in k_l1_node)
  float* fs2 = fd1 + (size_t)n*128;        // n*16
  float* fd2 = fs2 + (size_t)n*16;         // n*16
  float* res = fd2 + (size_t)n*16;         // n*16
  int* deg     = (int*)(res + (size_t)n*16); // n
  int* off     = deg + n;                    // n+1
  int* cur     = off + (n+1);                // n
  int* bsum    = cur + n;                    // scan block sums (<= 128)
  int* csr_src = bsum + 128;                 // ne

  const int nblk = (n + SCB - 1) / SCB;

  // ---- CSR build ----
  hipMemsetAsync(deg, 0, (size_t)n*4, stream);
  hipMemsetAsync(cur, 0, (size_t)n*4, stream);
  k_count  <<<(ne + 255)/256, 256, 0, stream>>>(dst, deg, ne);
  k_scan1  <<<nblk, SCB, 0, stream>>>(deg, off, bsum, n);
  k_scan2  <<<1, 64, 0, stream>>>(bsum, nblk);
  k_scan3  <<<nblk, SCB, 0, stream>>>(off, bsum, n, ne);
  k_scatter<<<(ne + 255)/256, 256, 0, stream>>>(src, dst, off, cur, csr_src, ne);

  // ---- layer 1 ----
  k_gemm1  <<<(n + GN1 - 1)/GN1, 128, 0, stream>>>(h, W1s, W1d, fs1, fd1, n);
  k_l1_node<<<(n + 3)/4, 256, 0, stream>>>(fs1, fd1, off, csr_src, a1, fd1, n);

  // ---- layer 2 (writes d_out directly) ----
  k_gemm2  <<<(n + 15)/16, 256, 0, stream>>>(fd1, W2s, W2d, Wres, fs2, fd2, res, n);
  k_l2_node<<<(n + 3)/4, 256, 0, stream>>>(fs2, fd2, res, off, csr_src, a2, out, n);
}

// Round 6
// 444.029 us; speedup vs baseline: 4.7070x; 1.2585x over previous
//
#include <hip/hip_runtime.h>
#include <hip/hip_bf16.h>

#define NEG 0.2f
#define FNEG_MAX -3.402823466e38f

// ============ CSR build ============
__global__ __launch_bounds__(256)
void k_count(const int* __restrict__ dst, int* __restrict__ deg, int ne){
  int e = blockIdx.x*256 + threadIdx.x;
  if (e < ne) atomicAdd(&deg[dst[e]], 1);
}

#define SCB 512
__global__ __launch_bounds__(SCB)
void k_scan1(const int* __restrict__ deg, int* __restrict__ off,
             int* __restrict__ bsum, int n){
  __shared__ int lds[SCB];
  int t = threadIdx.x, i = blockIdx.x*SCB + t;
  int x = (i < n) ? deg[i] : 0;
  lds[t] = x; __syncthreads();
  for (int s = 1; s < SCB; s <<= 1){
    int v = (t >= s) ? lds[t-s] : 0;
    __syncthreads();
    lds[t] += v;
    __syncthreads();
  }
  if (i < n) off[i] = lds[t] - x;            // exclusive
  if (t == SCB-1) bsum[blockIdx.x] = lds[t]; // block total
}

__global__ void k_scan2(int* __restrict__ bsum, int nblk){
  if (threadIdx.x == 0 && blockIdx.x == 0){
    int acc = 0;
    for (int b = 0; b < nblk; ++b){ int v = bsum[b]; bsum[b] = acc; acc += v; }
  }
}

__global__ __launch_bounds__(SCB)
void k_scan3(int* __restrict__ off, const int* __restrict__ bsum, int n, int ne){
  int i = blockIdx.x*SCB + threadIdx.x;
  if (i < n) off[i] += bsum[blockIdx.x];
  if (i == 0) off[n] = ne;
}

__global__ __launch_bounds__(256)
void k_scatter(const int* __restrict__ src, const int* __restrict__ dst,
               const int* __restrict__ off, int* __restrict__ cur,
               int* __restrict__ csr_src, int ne){
  int e = blockIdx.x*256 + threadIdx.x;
  if (e >= ne) return;
  int d = dst[e];
  int pos = off[d] + atomicAdd(&cur[d], 1);
  csr_src[pos] = src[e];
}

// ============ Layer 1 GEMM: fs = h@Ws, fd = h@Wd  (N x 128 @ 128 x 128) ======
#define GN1 16
__global__ __launch_bounds__(128)
void k_gemm1(const float* __restrict__ h, const float* __restrict__ Ws,
             const float* __restrict__ Wd, float* __restrict__ fs,
             float* __restrict__ fd, int n){
  __shared__ float hs[GN1][128];
  int col = threadIdx.x;
  int node0 = blockIdx.x * GN1;
  for (int i = 0; i < GN1; ++i){
    int nd = node0 + i;
    hs[i][col] = (nd < n) ? h[(size_t)nd*128 + col] : 0.f;
  }
  __syncthreads();
  float accs[GN1], accd[GN1];
  #pragma unroll
  for (int i = 0; i < GN1; ++i){ accs[i]=0.f; accd[i]=0.f; }
  for (int k = 0; k < 128; ++k){
    float ws = Ws[k*128 + col];
    float wd = Wd[k*128 + col];
    #pragma unroll
    for (int i = 0; i < GN1; ++i){
      accs[i] = fmaf(hs[i][k], ws, accs[i]);
      accd[i] = fmaf(hs[i][k], wd, accd[i]);
    }
  }
  for (int i = 0; i < GN1; ++i){
    int nd = node0 + i;
    if (nd < n){
      fs[(size_t)nd*128 + col] = accs[i];
      fd[(size_t)nd*128 + col] = accd[i];
    }
  }
}

// ============ Layer 1 fused: per-node online-softmax aggregate + ELU =========
// One wave per node. Lane l holds dims 2l,2l+1 (head = lane>>5).
// 4-edge chunking: 4 gathers in flight, butterfly reduce 4 independent values
// per step (overlapped cross-lane latency), one online rescale per 4 edges.
// NOTE: `fdv_` and `out` alias (fd1 reused as h1 output): each wave reads only
// its own node's fd row before writing that same row; rows are wave-private.
__global__ __launch_bounds__(256)
void k_l1_node(const float* __restrict__ fs, const float* fdv_,
               const int* __restrict__ off, const int* __restrict__ csr,
               const float* __restrict__ a1, float* out, int n){
  int wid  = (int)((blockIdx.x*256u + threadIdx.x) >> 6);
  int lane = threadIdx.x & 63;
  if (wid >= n) return;
  int d = wid;
  int e0 = off[d], e1 = off[d+1];
  float2 fdv = ((const float2*)fdv_)[(size_t)d*64 + lane];
  float2 aw  = ((const float2*)a1)[lane];
  float m = FNEG_MAX, den = 0.f;
  float ax = 0.f, ay = 0.f;

  int i = e0;
  for (; i + 4 <= e1; i += 4){
    int s0 = csr[i], s1 = csr[i+1], s2 = csr[i+2], s3 = csr[i+3];
    float2 v0 = ((const float2*)fs)[(size_t)s0*64 + lane];
    float2 v1 = ((const float2*)fs)[(size_t)s1*64 + lane];
    float2 v2 = ((const float2*)fs)[(size_t)s2*64 + lane];
    float2 v3 = ((const float2*)fs)[(size_t)s3*64 + lane];
    float p0, p1, p2, p3;
    {
      float x0 = v0.x + fdv.x, x1 = v0.y + fdv.y;
      x0 = x0 > 0.f ? x0 : NEG*x0;  x1 = x1 > 0.f ? x1 : NEG*x1;
      p0 = fmaf(x0, aw.x, x1*aw.y);
    }
    {
      float x0 = v1.x + fdv.x, x1 = v1.y + fdv.y;
      x0 = x0 > 0.f ? x0 : NEG*x0;  x1 = x1 > 0.f ? x1 : NEG*x1;
      p1 = fmaf(x0, aw.x, x1*aw.y);
    }
    {
      float x0 = v2.x + fdv.x, x1 = v2.y + fdv.y;
      x0 = x0 > 0.f ? x0 : NEG*x0;  x1 = x1 > 0.f ? x1 : NEG*x1;
      p2 = fmaf(x0, aw.x, x1*aw.y);
    }
    {
      float x0 = v3.x + fdv.x, x1 = v3.y + fdv.y;
      x0 = x0 > 0.f ? x0 : NEG*x0;  x1 = x1 > 0.f ? x1 : NEG*x1;
      p3 = fmaf(x0, aw.x, x1*aw.y);
    }
    // 5-step butterfly within each 32-lane head-half; 4 independent reductions
    // per step -> shfl latencies overlap.
    #pragma unroll
    for (int o = 16; o >= 1; o >>= 1){
      p0 += __shfl_xor(p0, o, 64);
      p1 += __shfl_xor(p1, o, 64);
      p2 += __shfl_xor(p2, o, 64);
      p3 += __shfl_xor(p3, o, 64);
    }
    // one online-softmax rescale for the 4 edges (identical math to sequential)
    float mx = fmaxf(fmaxf(p0, p1), fmaxf(p2, p3));
    float nm = fmaxf(m, mx);
    float scale = __expf(m - nm);
    float w0 = __expf(p0 - nm), w1 = __expf(p1 - nm);
    float w2 = __expf(p2 - nm), w3 = __expf(p3 - nm);
    den = fmaf(den, scale, (w0 + w1) + (w2 + w3));
    float gx = fmaf(w0, v0.x, w1*v1.x) + fmaf(w2, v2.x, w3*v3.x);
    float gy = fmaf(w0, v0.y, w1*v1.y) + fmaf(w2, v2.y, w3*v3.y);
    ax = fmaf(ax, scale, gx);
    ay = fmaf(ay, scale, gy);
    m = nm;
  }
  for (; i < e1; ++i){
    int s = csr[i];
    float2 v = ((const float2*)fs)[(size_t)s*64 + lane];
    float x0 = v.x + fdv.x, x1 = v.y + fdv.y;
    x0 = x0 > 0.f ? x0 : NEG*x0;
    x1 = x1 > 0.f ? x1 : NEG*x1;
    float p = fmaf(x0, aw.x, x1*aw.y);
    #pragma unroll
    for (int o = 16; o >= 1; o >>= 1) p += __shfl_xor(p, o, 64);
    float nm    = fmaxf(m, p);
    float scale = __expf(m - nm);
    float w     = __expf(p - nm);
    den = fmaf(den, scale, w);
    ax  = fmaf(ax, scale, w*v.x);
    ay  = fmaf(ay, scale, w*v.y);
    m = nm;
  }

  float inv = (den > 0.f) ? 1.f/den : 0.f;
  float y0 = ax*inv, y1 = ay*inv;
  y0 = y0 > 0.f ? y0 : __expf(y0) - 1.f;   // ELU fused
  y1 = y1 > 0.f ? y1 : __expf(y1) - 1.f;
  ((float2*)out)[(size_t)d*64 + lane] = make_float2(y0, y1);
}

// ============ Layer 2 GEMM: fs2/fd2/res = h1 @ {W2s,W2d,Wr} (128 -> 16) ======
__global__ __launch_bounds__(256)
void k_gemm2(const float* __restrict__ h1, const float* __restrict__ Ws,
             const float* __restrict__ Wd, const float* __restrict__ Wr,
             float* __restrict__ fs2, float* __restrict__ fd2,
             float* __restrict__ res, int n){
  __shared__ float hs[16][129];
  __shared__ float w[3][128][16];
  int tid = threadIdx.x;
  for (int i = tid; i < 2048; i += 256){
    int k = i >> 4, j = i & 15;
    w[0][k][j] = Ws[i]; w[1][k][j] = Wd[i]; w[2][k][j] = Wr[i];
  }
  int node0 = blockIdx.x * 16;
  for (int i = tid; i < 2048; i += 256){
    int r = i >> 7, c = i & 127;
    int nd = node0 + r;
    hs[r][c] = (nd < n) ? h1[(size_t)nd*128 + c] : 0.f;
  }
  __syncthreads();
  int j = tid & 15, ni = tid >> 4;
  float as = 0.f, ad = 0.f, ar = 0.f;
  for (int k = 0; k < 128; ++k){
    float hv = hs[ni][k];
    as = fmaf(hv, w[0][k][j], as);
    ad = fmaf(hv, w[1][k][j], ad);
    ar = fmaf(hv, w[2][k][j], ar);
  }
  int nd = node0 + ni;
  if (nd < n){
    fs2[(size_t)nd*16 + j] = as;
    fd2[(size_t)nd*16 + j] = ad;
    res[(size_t)nd*16 + j] = ar;
  }
}

// ============ Layer 2 fused: per-node online softmax + residual -> d_out =====
// One wave per node; 4 groups of 16 lanes process edges strided, then merge.
__global__ __launch_bounds__(256)
void k_l2_node(const float* __restrict__ fs2, const float* __restrict__ fd2,
               const float* __restrict__ resd, const int* __restrict__ off,
               const int* __restrict__ csr, const float* __restrict__ a2,
               float* __restrict__ outp, int n){
  int wid  = (int)((blockIdx.x*256u + threadIdx.x) >> 6);
  int lane = threadIdx.x & 63;
  if (wid >= n) return;
  int d = wid;
  int g = lane >> 4, j = lane & 15;
  int e0 = off[d], e1 = off[d+1];
  float fdv = fd2[(size_t)d*16 + j];
  float aw  = a2[j];
  float m = FNEG_MAX, den = 0.f, acc = 0.f;
  for (int i = e0 + g; i < e1; i += 4){
    int s = csr[i];
    float v = fs2[(size_t)s*16 + j];
    float x = v + fdv; x = x > 0.f ? x : NEG*x;
    float p = x * aw;
    #pragma unroll
    for (int o = 8; o >= 1; o >>= 1) p += __shfl_xor(p, o, 64);
    float nm = fmaxf(m, p);
    float sc = __expf(m - nm);
    float w  = __expf(p - nm);
    den = den*sc + w;
    acc = acc*sc + w*v;
    m = nm;
  }
  // merge the 4 groups' (m, den, acc): butterfly xor 16 then 32
  #pragma unroll
  for (int o = 16; o <= 32; o <<= 1){
    float om   = __shfl_xor(m,   o, 64);
    float oden = __shfl_xor(den, o, 64);
    float oacc = __shfl_xor(acc, o, 64);
    float nm = fmaxf(m, om);
    float s1 = __expf(m - nm);    // -FLT_MAX sentinel: exp underflows to 0 safely
    float s2 = __expf(om - nm);
    den = den*s1 + oden*s2;
    acc = acc*s1 + oacc*s2;
    m = nm;
  }
  if (g == 0){
    float inv = (den > 0.f) ? 1.f/den : 0.f;
    outp[(size_t)d*16 + j] = acc*inv + resd[(size_t)d*16 + j];
  }
}

extern "C" void kernel_launch(void* const* d_in, const int* in_sizes, int n_in,
                              void* d_out, int out_size, void* d_ws, size_t ws_size,
                              hipStream_t stream) {
  const float* h    = (const float*)d_in[0];
  const int*   src  = (const int*)  d_in[1];
  const int*   dst  = (const int*)  d_in[2];
  const float* W1s  = (const float*)d_in[3];
  const float* W1d  = (const float*)d_in[4];
  const float* a1   = (const float*)d_in[5];
  const float* W2s  = (const float*)d_in[6];
  const float* W2d  = (const float*)d_in[7];
  const float* a2   = (const float*)d_in[8];
  const float* Wres = (const float*)d_in[9];
  float* out = (float*)d_out;

  const int n  = in_sizes[0] / 128;   // 50000
  const int ne = in_sizes[1];         // 1600000

  // ---- workspace layout ----
  float* ws  = (float*)d_ws;
  float* fs1 = ws;                         // n*128
  float* fd1 = fs1 + (size_t)n*128;        // n*128 (becomes h1 in k_l1_node)
  float* fs2 = fd1 + (size_t)n*128;        // n*16
  float* fd2 = fs2 + (size_t)n*16;         // n*16
  float* res = fd2 + (size_t)n*16;         // n*16
  int* deg     = (int*)(res + (size_t)n*16); // n
  int* off     = deg + n;                    // n+1
  int* cur     = off + (n+1);                // n
  int* bsum    = cur + n;                    // scan block sums (<= 128)
  int* csr_src = bsum + 128;                 // ne

  const int nblk = (n + SCB - 1) / SCB;

  // ---- CSR build ----
  hipMemsetAsync(deg, 0, (size_t)n*4, stream);
  hipMemsetAsync(cur, 0, (size_t)n*4, stream);
  k_count  <<<(ne + 255)/256, 256, 0, stream>>>(dst, deg, ne);
  k_scan1  <<<nblk, SCB, 0, stream>>>(deg, off, bsum, n);
  k_scan2  <<<1, 64, 0, stream>>>(bsum, nblk);
  k_scan3  <<<nblk, SCB, 0, stream>>>(off, bsum, n, ne);
  k_scatter<<<(ne + 255)/256, 256, 0, stream>>>(src, dst, off, cur, csr_src, ne);

  // ---- layer 1 ----
  k_gemm1  <<<(n + GN1 - 1)/GN1, 128, 0, stream>>>(h, W1s, W1d, fs1, fd1, n);
  k_l1_node<<<(n + 3)/4, 256, 0, stream>>>(fs1, fd1, off, csr_src, a1, fd1, n);

  // ---- layer 2 (writes d_out directly) ----
  k_gemm2  <<<(n + 15)/16, 256, 0, stream>>>(fd1, W2s, W2d, Wres, fs2, fd2, res, n);
  k_l2_node<<<(n + 3)/4, 256, 0, stream>>>(fs2, fd2, res, off, csr_src, a2, out, n);
}

// Round 7
// 417.663 us; speedup vs baseline: 5.0041x; 1.0631x over previous
//
#include <hip/hip_runtime.h>
#include <hip/hip_bf16.h>

#define NEG 0.2f
#define FNEG_MAX -3.402823466e38f

// ============ CSR build ============
__global__ __launch_bounds__(256)
void k_count(const int* __restrict__ dst, int* __restrict__ deg, int ne){
  int e = blockIdx.x*256 + threadIdx.x;
  if (e < ne) atomicAdd(&deg[dst[e]], 1);
}

#define SCB 512
__global__ __launch_bounds__(SCB)
void k_scan1(const int* __restrict__ deg, int* __restrict__ off,
             int* __restrict__ bsum, int n){
  __shared__ int lds[SCB];
  int t = threadIdx.x, i = blockIdx.x*SCB + t;
  int x = (i < n) ? deg[i] : 0;
  lds[t] = x; __syncthreads();
  for (int s = 1; s < SCB; s <<= 1){
    int v = (t >= s) ? lds[t-s] : 0;
    __syncthreads();
    lds[t] += v;
    __syncthreads();
  }
  if (i < n) off[i] = lds[t] - x;            // exclusive
  if (t == SCB-1) bsum[blockIdx.x] = lds[t]; // block total
}

__global__ void k_scan2(int* __restrict__ bsum, int nblk){
  if (threadIdx.x == 0 && blockIdx.x == 0){
    int acc = 0;
    for (int b = 0; b < nblk; ++b){ int v = bsum[b]; bsum[b] = acc; acc += v; }
  }
}

__global__ __launch_bounds__(SCB)
void k_scan3(int* __restrict__ off, const int* __restrict__ bsum, int n, int ne){
  int i = blockIdx.x*SCB + threadIdx.x;
  if (i < n) off[i] += bsum[blockIdx.x];
  if (i == 0) off[n] = ne;
}

__global__ __launch_bounds__(256)
void k_scatter(const int* __restrict__ src, const int* __restrict__ dst,
               const int* __restrict__ off, int* __restrict__ cur,
               int* __restrict__ csr_src, int ne){
  int e = blockIdx.x*256 + threadIdx.x;
  if (e >= ne) return;
  int d = dst[e];
  int pos = off[d] + atomicAdd(&cur[d], 1);
  csr_src[pos] = src[e];
}

// ============ Layer 1 GEMM: fs = h@Ws, fd = h@Wd  (N x 128 @ 128 x 128) ======
// 32 nodes/block, 256 threads. h staged TRANSPOSED in LDS (ht[k][node], pad 36
// -> 16B-aligned rows, write conflicts 8-way but amortized). Thread tile:
// 8 nodes x 4 cols x 1 mat. Per k: 1 global dwordx4 (weights) + 2 ds_read_b128
// + 32 fma -> VALU-bound near the fp32 floor.
#define GM1 32
__global__ __launch_bounds__(256)
void k_gemm1(const float* __restrict__ h, const float* __restrict__ Ws,
             const float* __restrict__ Wd, float* __restrict__ fs,
             float* __restrict__ fd, int n){
  __shared__ float ht[128][36];
  int tid = threadIdx.x;
  int node0 = blockIdx.x * GM1;
  for (int i = tid; i < GM1*128; i += 256){
    int r = i >> 7, c = i & 127;
    int nd = node0 + r;
    ht[c][r] = (nd < n) ? h[(size_t)nd*128 + c] : 0.f;
  }
  __syncthreads();
  int cg  = tid & 31;          // 4-col group: cols 4*cg..4*cg+3
  int mat = (tid >> 5) & 1;    // 0: Ws, 1: Wd
  int q   = tid >> 6;          // node quarter: nodes q*8..q*8+7 (wave-uniform)
  const float4* W4 = (const float4*)(mat ? Wd : Ws);
  float4*       F4 = (float4*)(mat ? fd : fs);
  float acc[8][4];
  #pragma unroll
  for (int j = 0; j < 8; ++j){ acc[j][0]=0.f; acc[j][1]=0.f; acc[j][2]=0.f; acc[j][3]=0.f; }
  for (int k = 0; k < 128; ++k){
    float4 w = W4[k*32 + cg];
    const float4* hp4 = (const float4*)&ht[k][q*8];
    float4 ha = hp4[0], hb = hp4[1];
    float hv[8] = {ha.x, ha.y, ha.z, ha.w, hb.x, hb.y, hb.z, hb.w};
    #pragma unroll
    for (int j = 0; j < 8; ++j){
      acc[j][0] = fmaf(hv[j], w.x, acc[j][0]);
      acc[j][1] = fmaf(hv[j], w.y, acc[j][1]);
      acc[j][2] = fmaf(hv[j], w.z, acc[j][2]);
      acc[j][3] = fmaf(hv[j], w.w, acc[j][3]);
    }
  }
  #pragma unroll
  for (int j = 0; j < 8; ++j){
    int nd = node0 + q*8 + j;
    if (nd < n){
      float4 o; o.x=acc[j][0]; o.y=acc[j][1]; o.z=acc[j][2]; o.w=acc[j][3];
      F4[(size_t)nd*32 + cg] = o;
    }
  }
}

// ============ Layer 1 fused: per-node online-softmax aggregate + ELU =========
// One wave per node. Lane l holds dims 2l,2l+1 (head = lane>>5).
// 8-edge chunking: one lane-strided csr load + readlane -> SGPR indices
// (scalar address math, saddr gathers), 8 gathers in flight, butterfly
// reduces 8 independent values per step, one online rescale per 8 edges.
// NOTE: `fdv_` and `out` alias (fd1 reused as h1 output): each wave reads only
// its own node's fd row before writing that same row; rows are wave-private.
__global__ __launch_bounds__(256)
void k_l1_node(const float* __restrict__ fs, const float* fdv_,
               const int* __restrict__ off, const int* __restrict__ csr,
               const float* __restrict__ a1, float* out, int n){
  int wid  = (int)((blockIdx.x*256u + threadIdx.x) >> 6);
  int lane = threadIdx.x & 63;
  if (wid >= n) return;
  int d = wid;
  int e0 = off[d], e1 = off[d+1];
  float2 fdv = ((const float2*)fdv_)[(size_t)d*64 + lane];
  float2 aw  = ((const float2*)a1)[lane];
  float m = FNEG_MAX, den = 0.f;
  float ax = 0.f, ay = 0.f;

  const char* fsb = (const char*)fs;
  size_t lo = (size_t)(lane*8);

  int i = e0;
  for (; i + 8 <= e1; i += 8){
    int sv = csr[i + (lane & 7)];
    int s0 = __builtin_amdgcn_readlane(sv, 0);
    int s1 = __builtin_amdgcn_readlane(sv, 1);
    int s2 = __builtin_amdgcn_readlane(sv, 2);
    int s3 = __builtin_amdgcn_readlane(sv, 3);
    int s4 = __builtin_amdgcn_readlane(sv, 4);
    int s5 = __builtin_amdgcn_readlane(sv, 5);
    int s6 = __builtin_amdgcn_readlane(sv, 6);
    int s7 = __builtin_amdgcn_readlane(sv, 7);
    float2 v0 = *(const float2*)(fsb + ((size_t)s0*512 + lo));
    float2 v1 = *(const float2*)(fsb + ((size_t)s1*512 + lo));
    float2 v2 = *(const float2*)(fsb + ((size_t)s2*512 + lo));
    float2 v3 = *(const float2*)(fsb + ((size_t)s3*512 + lo));
    float2 v4 = *(const float2*)(fsb + ((size_t)s4*512 + lo));
    float2 v5 = *(const float2*)(fsb + ((size_t)s5*512 + lo));
    float2 v6 = *(const float2*)(fsb + ((size_t)s6*512 + lo));
    float2 v7 = *(const float2*)(fsb + ((size_t)s7*512 + lo));
    float p0,p1,p2,p3,p4,p5,p6,p7;
    #define SCORE(P,V) { \
      float x0 = V.x + fdv.x, x1 = V.y + fdv.y; \
      x0 = x0 > 0.f ? x0 : NEG*x0;  x1 = x1 > 0.f ? x1 : NEG*x1; \
      P = fmaf(x0, aw.x, x1*aw.y); }
    SCORE(p0,v0) SCORE(p1,v1) SCORE(p2,v2) SCORE(p3,v3)
    SCORE(p4,v4) SCORE(p5,v5) SCORE(p6,v6) SCORE(p7,v7)
    #undef SCORE
    #pragma unroll
    for (int o = 16; o >= 1; o >>= 1){
      p0 += __shfl_xor(p0, o, 64);
      p1 += __shfl_xor(p1, o, 64);
      p2 += __shfl_xor(p2, o, 64);
      p3 += __shfl_xor(p3, o, 64);
      p4 += __shfl_xor(p4, o, 64);
      p5 += __shfl_xor(p5, o, 64);
      p6 += __shfl_xor(p6, o, 64);
      p7 += __shfl_xor(p7, o, 64);
    }
    float mx = fmaxf(fmaxf(fmaxf(p0,p1), fmaxf(p2,p3)),
                     fmaxf(fmaxf(p4,p5), fmaxf(p6,p7)));
    float nm = fmaxf(m, mx);
    float scale = __expf(m - nm);
    float w0 = __expf(p0-nm), w1 = __expf(p1-nm), w2 = __expf(p2-nm), w3 = __expf(p3-nm);
    float w4 = __expf(p4-nm), w5 = __expf(p5-nm), w6 = __expf(p6-nm), w7 = __expf(p7-nm);
    den = fmaf(den, scale, ((w0+w1)+(w2+w3)) + ((w4+w5)+(w6+w7)));
    float gx = (fmaf(w0,v0.x,w1*v1.x) + fmaf(w2,v2.x,w3*v3.x))
             + (fmaf(w4,v4.x,w5*v5.x) + fmaf(w6,v6.x,w7*v7.x));
    float gy = (fmaf(w0,v0.y,w1*v1.y) + fmaf(w2,v2.y,w3*v3.y))
             + (fmaf(w4,v4.y,w5*v5.y) + fmaf(w6,v6.y,w7*v7.y));
    ax = fmaf(ax, scale, gx);
    ay = fmaf(ay, scale, gy);
    m = nm;
  }
  for (; i < e1; ++i){
    int s = csr[i];
    float2 v = *(const float2*)(fsb + ((size_t)s*512 + lo));
    float x0 = v.x + fdv.x, x1 = v.y + fdv.y;
    x0 = x0 > 0.f ? x0 : NEG*x0;
    x1 = x1 > 0.f ? x1 : NEG*x1;
    float p = fmaf(x0, aw.x, x1*aw.y);
    #pragma unroll
    for (int o = 16; o >= 1; o >>= 1) p += __shfl_xor(p, o, 64);
    float nm    = fmaxf(m, p);
    float scale = __expf(m - nm);
    float w     = __expf(p - nm);
    den = fmaf(den, scale, w);
    ax  = fmaf(ax, scale, w*v.x);
    ay  = fmaf(ay, scale, w*v.y);
    m = nm;
  }

  float inv = (den > 0.f) ? 1.f/den : 0.f;
  float y0 = ax*inv, y1 = ay*inv;
  y0 = y0 > 0.f ? y0 : __expf(y0) - 1.f;   // ELU fused
  y1 = y1 > 0.f ? y1 : __expf(y1) - 1.f;
  ((float2*)out)[(size_t)d*64 + lane] = make_float2(y0, y1);
}

// ============ Layer 2 GEMM: fs2/fd2/res = h1 @ {W2s,W2d,Wr} (128 -> 16) ======
__global__ __launch_bounds__(256)
void k_gemm2(const float* __restrict__ h1, const float* __restrict__ Ws,
             const float* __restrict__ Wd, const float* __restrict__ Wr,
             float* __restrict__ fs2, float* __restrict__ fd2,
             float* __restrict__ res, int n){
  __shared__ float hs[16][129];
  __shared__ float w[3][128][16];
  int tid = threadIdx.x;
  for (int i = tid; i < 2048; i += 256){
    int k = i >> 4, j = i & 15;
    w[0][k][j] = Ws[i]; w[1][k][j] = Wd[i]; w[2][k][j] = Wr[i];
  }
  int node0 = blockIdx.x * 16;
  for (int i = tid; i < 2048; i += 256){
    int r = i >> 7, c = i & 127;
    int nd = node0 + r;
    hs[r][c] = (nd < n) ? h1[(size_t)nd*128 + c] : 0.f;
  }
  __syncthreads();
  int j = tid & 15, ni = tid >> 4;
  float as = 0.f, ad = 0.f, ar = 0.f;
  for (int k = 0; k < 128; ++k){
    float hv = hs[ni][k];
    as = fmaf(hv, w[0][k][j], as);
    ad = fmaf(hv, w[1][k][j], ad);
    ar = fmaf(hv, w[2][k][j], ar);
  }
  int nd = node0 + ni;
  if (nd < n){
    fs2[(size_t)nd*16 + j] = as;
    fd2[(size_t)nd*16 + j] = ad;
    res[(size_t)nd*16 + j] = ar;
  }
}

// ============ Layer 2 fused: per-node online softmax + residual -> d_out =====
// One wave per node; 4 groups of 16 lanes process edges strided, then merge.
__global__ __launch_bounds__(256)
void k_l2_node(const float* __restrict__ fs2, const float* __restrict__ fd2,
               const float* __restrict__ resd, const int* __restrict__ off,
               const int* __restrict__ csr, const float* __restrict__ a2,
               float* __restrict__ outp, int n){
  int wid  = (int)((blockIdx.x*256u + threadIdx.x) >> 6);
  int lane = threadIdx.x & 63;
  if (wid >= n) return;
  int d = wid;
  int g = lane >> 4, j = lane & 15;
  int e0 = off[d], e1 = off[d+1];
  float fdv = fd2[(size_t)d*16 + j];
  float aw  = a2[j];
  float m = FNEG_MAX, den = 0.f, acc = 0.f;
  for (int i = e0 + g; i < e1; i += 4){
    int s = csr[i];
    float v = fs2[(size_t)s*16 + j];
    float x = v + fdv; x = x > 0.f ? x : NEG*x;
    float p = x * aw;
    #pragma unroll
    for (int o = 8; o >= 1; o >>= 1) p += __shfl_xor(p, o, 64);
    float nm = fmaxf(m, p);
    float sc = __expf(m - nm);
    float w  = __expf(p - nm);
    den = den*sc + w;
    acc = acc*sc + w*v;
    m = nm;
  }
  // merge the 4 groups' (m, den, acc): butterfly xor 16 then 32
  #pragma unroll
  for (int o = 16; o <= 32; o <<= 1){
    float om   = __shfl_xor(m,   o, 64);
    float oden = __shfl_xor(den, o, 64);
    float oacc = __shfl_xor(acc, o, 64);
    float nm = fmaxf(m, om);
    float s1 = __expf(m - nm);    // -FLT_MAX sentinel: exp underflows to 0 safely
    float s2 = __expf(om - nm);
    den = den*s1 + oden*s2;
    acc = acc*s1 + oacc*s2;
    m = nm;
  }
  if (g == 0){
    float inv = (den > 0.f) ? 1.f/den : 0.f;
    outp[(size_t)d*16 + j] = acc*inv + resd[(size_t)d*16 + j];
  }
}

extern "C" void kernel_launch(void* const* d_in, const int* in_sizes, int n_in,
                              void* d_out, int out_size, void* d_ws, size_t ws_size,
                              hipStream_t stream) {
  const float* h    = (const float*)d_in[0];
  const int*   src  = (const int*)  d_in[1];
  const int*   dst  = (const int*)  d_in[2];
  const float* W1s  = (const float*)d_in[3];
  const float* W1d  = (const float*)d_in[4];
  const float* a1   = (const float*)d_in[5];
  const float* W2s  = (const float*)d_in[6];
  const float* W2d  = (const float*)d_in[7];
  const float* a2   = (const float*)d_in[8];
  const float* Wres = (const float*)d_in[9];
  float* out = (float*)d_out;

  const int n  = in_sizes[0] / 128;   // 50000
  const int ne = in_sizes[1];         // 1600000

  // ---- workspace layout ----
  float* ws  = (float*)d_ws;
  float* fs1 = ws;                         // n*128
  float* fd1 = fs1 + (size_t)n*128;        // n*128 (becomes h1 in k_l1_node)
  float* fs2 = fd1 + (size_t)n*128;        // n*16
  float* fd2 = fs2 + (size_t)n*16;         // n*16
  float* res = fd2 + (size_t)n*16;         // n*16
  int* deg     = (int*)(res + (size_t)n*16); // n
  int* off     = deg + n;                    // n+1
  int* cur     = off + (n+1);                // n
  int* bsum    = cur + n;                    // scan block sums (<= 128)
  int* csr_src = bsum + 128;                 // ne

  const int nblk = (n + SCB - 1) / SCB;

  // ---- CSR build ----
  hipMemsetAsync(deg, 0, (size_t)n*4, stream);
  hipMemsetAsync(cur, 0, (size_t)n*4, stream);
  k_count  <<<(ne + 255)/256, 256, 0, stream>>>(dst, deg, ne);
  k_scan1  <<<nblk, SCB, 0, stream>>>(deg, off, bsum, n);
  k_scan2  <<<1, 64, 0, stream>>>(bsum, nblk);
  k_scan3  <<<nblk, SCB, 0, stream>>>(off, bsum, n, ne);
  k_scatter<<<(ne + 255)/256, 256, 0, stream>>>(src, dst, off, cur, csr_src, ne);

  // ---- layer 1 ----
  k_gemm1  <<<(n + GM1 - 1)/GM1, 256, 0, stream>>>(h, W1s, W1d, fs1, fd1, n);
  k_l1_node<<<(n + 3)/4, 256, 0, stream>>>(fs1, fd1, off, csr_src, a1, fd1, n);

  // ---- layer 2 (writes d_out directly) ----
  k_gemm2  <<<(n + 15)/16, 256, 0, stream>>>(fd1, W2s, W2d, Wres, fs2, fd2, res, n);
  k_l2_node<<<(n + 3)/4, 256, 0, stream>>>(fs2, fd2, res, off, csr_src, a2, out, n);
}

// Round 11
// 416.204 us; speedup vs baseline: 5.0217x; 1.0035x over previous
//
#include <hip/hip_runtime.h>
#include <hip/hip_bf16.h>

#define NEG 0.2f
#define FNEG_MAX -3.402823466e38f

// ============ CSR build ============
__global__ __launch_bounds__(256)
void k_count(const int* __restrict__ dst, int* __restrict__ deg, int ne){
  int e = blockIdx.x*256 + threadIdx.x;
  if (e < ne) atomicAdd(&deg[dst[e]], 1);
}

#define SCB 512
__global__ __launch_bounds__(SCB)
void k_scan1(const int* __restrict__ deg, int* __restrict__ off,
             int* __restrict__ bsum, int n){
  __shared__ int lds[SCB];
  int t = threadIdx.x, i = blockIdx.x*SCB + t;
  int x = (i < n) ? deg[i] : 0;
  lds[t] = x; __syncthreads();
  for (int s = 1; s < SCB; s <<= 1){
    int v = (t >= s) ? lds[t-s] : 0;
    __syncthreads();
    lds[t] += v;
    __syncthreads();
  }
  if (i < n) off[i] = lds[t] - x;            // exclusive
  if (t == SCB-1) bsum[blockIdx.x] = lds[t]; // block total
}

__global__ void k_scan2(int* __restrict__ bsum, int nblk){
  if (threadIdx.x == 0 && blockIdx.x == 0){
    int acc = 0;
    for (int b = 0; b < nblk; ++b){ int v = bsum[b]; bsum[b] = acc; acc += v; }
  }
}

__global__ __launch_bounds__(SCB)
void k_scan3(int* __restrict__ off, const int* __restrict__ bsum, int n, int ne){
  int i = blockIdx.x*SCB + threadIdx.x;
  if (i < n) off[i] += bsum[blockIdx.x];
  if (i == 0) off[n] = ne;
}

__global__ __launch_bounds__(256)
void k_scatter(const int* __restrict__ src, const int* __restrict__ dst,
               const int* __restrict__ off, int* __restrict__ cur,
               int* __restrict__ csr_src, int ne){
  int e = blockIdx.x*256 + threadIdx.x;
  if (e >= ne) return;
  int d = dst[e];
  int pos = off[d] + atomicAdd(&cur[d], 1);
  csr_src[pos] = src[e];
}

// ============ Layer 1 GEMM: fs = h@Ws, fd = h@Wd  (N x 128 @ 128 x 128) ======
#define GM1 32
__global__ __launch_bounds__(256)
void k_gemm1(const float* __restrict__ h, const float* __restrict__ Ws,
             const float* __restrict__ Wd, float* __restrict__ fs,
             float* __restrict__ fd, int n){
  __shared__ float ht[128][36];
  int tid = threadIdx.x;
  int node0 = blockIdx.x * GM1;
  for (int i = tid; i < GM1*128; i += 256){
    int r = i >> 7, c = i & 127;
    int nd = node0 + r;
    ht[c][r] = (nd < n) ? h[(size_t)nd*128 + c] : 0.f;
  }
  __syncthreads();
  int cg  = tid & 31;          // 4-col group: cols 4*cg..4*cg+3
  int mat = (tid >> 5) & 1;    // 0: Ws, 1: Wd
  int q   = tid >> 6;          // node quarter: nodes q*8..q*8+7 (wave-uniform)
  const float4* W4 = (const float4*)(mat ? Wd : Ws);
  float4*       F4 = (float4*)(mat ? fd : fs);
  float acc[8][4];
  #pragma unroll
  for (int j = 0; j < 8; ++j){ acc[j][0]=0.f; acc[j][1]=0.f; acc[j][2]=0.f; acc[j][3]=0.f; }
  for (int k = 0; k < 128; ++k){
    float4 w = W4[k*32 + cg];
    const float4* hp4 = (const float4*)&ht[k][q*8];
    float4 ha = hp4[0], hb = hp4[1];
    float hv[8] = {ha.x, ha.y, ha.z, ha.w, hb.x, hb.y, hb.z, hb.w};
    #pragma unroll
    for (int j = 0; j < 8; ++j){
      acc[j][0] = fmaf(hv[j], w.x, acc[j][0]);
      acc[j][1] = fmaf(hv[j], w.y, acc[j][1]);
      acc[j][2] = fmaf(hv[j], w.z, acc[j][2]);
      acc[j][3] = fmaf(hv[j], w.w, acc[j][3]);
    }
  }
  #pragma unroll
  for (int j = 0; j < 8; ++j){
    int nd = node0 + q*8 + j;
    if (nd < n){
      float4 o; o.x=acc[j][0]; o.y=acc[j][1]; o.z=acc[j][2]; o.w=acc[j][3];
      F4[(size_t)nd*32 + cg] = o;
    }
  }
}

// ============ Layer 1 fused: per-node online-softmax aggregate + ELU =========
// 32 lanes per edge, float4 per lane (lane lp owns dims 4lp..4lp+3; head =
// lp>>4). Wave = 2 edges at once (half-waves); butterfly = 4 steps within
// 16-lane head groups, shared by both edges -> 2 shfl/edge. Defer-max online
// softmax: m stays fixed unless __any(p > m + THR); rescale is rare.
// Validity masks (w=0) replace tail code. FNEG_MAX (finite) sentinel keeps
// p-m = 0 (not NaN) on degenerate paths. Halves merged at the end.
// NOTE: `fdv_` and `out` alias (fd1 reused as h1 output): wave-private rows.
#define THR1 10.f
__global__ __launch_bounds__(256)
void k_l1_node(const float* __restrict__ fs, const float* fdv_,
               const int* __restrict__ off, const int* __restrict__ csr,
               const float* __restrict__ a1, float* out, int n){
  int wid  = (int)((blockIdx.x*256u + threadIdx.x) >> 6);
  int lane = threadIdx.x & 63;
  if (wid >= n) return;
  int d  = wid;
  int hh = lane >> 5;       // which edge of the pair
  int lp = lane & 31;       // dims 4lp..4lp+3 of the edge row
  int e0 = off[d], e1 = off[d+1];
  int deg = e1 - e0;
  const float4* fs4 = (const float4*)fs;
  float4 fdv = ((const float4*)fdv_)[(size_t)d*32 + lp];
  float4 aw  = ((const float4*)a1)[lp];
  float m = FNEG_MAX, den = 0.f;
  float4 acc = make_float4(0.f, 0.f, 0.f, 0.f);

  int nt = (deg + 3) & ~3;   // multiple of 4 edges (2 iters of 2)
  for (int k = 0; k < nt; k += 4){
    int eiA = e0 + k + hh;
    int eiB = eiA + 2;
    bool vA = eiA < e1, vB = eiB < e1;
    int sA = csr[vA ? eiA : e0];
    int sB = csr[vB ? eiB : e0];
    float4 xA = fs4[(size_t)sA*32 + lp];
    float4 xB = fs4[(size_t)sB*32 + lp];
    float pA, pB;
    {
      float t0 = xA.x + fdv.x, t1 = xA.y + fdv.y;
      float t2 = xA.z + fdv.z, t3 = xA.w + fdv.w;
      t0 = fmaxf(t0, NEG*t0); t1 = fmaxf(t1, NEG*t1);
      t2 = fmaxf(t2, NEG*t2); t3 = fmaxf(t3, NEG*t3);
      pA = fmaf(t0, aw.x, fmaf(t1, aw.y, fmaf(t2, aw.z, t3*aw.w)));
    }
    {
      float t0 = xB.x + fdv.x, t1 = xB.y + fdv.y;
      float t2 = xB.z + fdv.z, t3 = xB.w + fdv.w;
      t0 = fmaxf(t0, NEG*t0); t1 = fmaxf(t1, NEG*t1);
      t2 = fmaxf(t2, NEG*t2); t3 = fmaxf(t3, NEG*t3);
      pB = fmaf(t0, aw.x, fmaf(t1, aw.y, fmaf(t2, aw.z, t3*aw.w)));
    }
    // 4-step butterfly within 16-lane head groups; both edges in parallel
    #pragma unroll
    for (int o = 8; o >= 1; o >>= 1){
      pA += __shfl_xor(pA, o, 64);
      pB += __shfl_xor(pB, o, 64);
    }
    pA = vA ? pA : FNEG_MAX;
    pB = vB ? pB : FNEG_MAX;
    float pmax = fmaxf(pA, pB);
    if (__any(pmax > m + THR1)){         // rare rescale
      float nm = fmaxf(m, pmax);
      float sc = __expf(m - nm);         // m==FNEG_MAX -> exp underflows to 0
      den *= sc;
      acc.x *= sc; acc.y *= sc; acc.z *= sc; acc.w *= sc;
      m = nm;
    }
    float wA = vA ? __expf(pA - m) : 0.f;
    float wB = vB ? __expf(pB - m) : 0.f;
    den += wA + wB;
    acc.x = fmaf(wA, xA.x, fmaf(wB, xB.x, acc.x));
    acc.y = fmaf(wA, xA.y, fmaf(wB, xB.y, acc.y));
    acc.z = fmaf(wA, xA.z, fmaf(wB, xB.z, acc.z));
    acc.w = fmaf(wA, xA.w, fmaf(wB, xB.w, acc.w));
  }

  // merge the two half-wave partials (per (node,dim), different edge subsets)
  float om   = __shfl_xor(m,   32, 64);
  float oden = __shfl_xor(den, 32, 64);
  float4 oacc;
  oacc.x = __shfl_xor(acc.x, 32, 64);
  oacc.y = __shfl_xor(acc.y, 32, 64);
  oacc.z = __shfl_xor(acc.z, 32, 64);
  oacc.w = __shfl_xor(acc.w, 32, 64);
  float nm = fmaxf(m, om);
  float s1 = __expf(m - nm), s2 = __expf(om - nm);  // deg==0: exp(0)=1, den=0
  den = den*s1 + oden*s2;
  float4 r;
  r.x = acc.x*s1 + oacc.x*s2;
  r.y = acc.y*s1 + oacc.y*s2;
  r.z = acc.z*s1 + oacc.z*s2;
  r.w = acc.w*s1 + oacc.w*s2;
  float inv = (den > 0.f) ? 1.f/den : 0.f;
  r.x *= inv; r.y *= inv; r.z *= inv; r.w *= inv;
  r.x = r.x > 0.f ? r.x : __expf(r.x) - 1.f;   // ELU fused
  r.y = r.y > 0.f ? r.y : __expf(r.y) - 1.f;
  r.z = r.z > 0.f ? r.z : __expf(r.z) - 1.f;
  r.w = r.w > 0.f ? r.w : __expf(r.w) - 1.f;
  if (hh == 0) ((float4*)out)[(size_t)d*32 + lp] = r;
}

// ============ Layer 2 GEMM: fs2/fd2/res = h1 @ {W2s,W2d,Wr} (128 -> 16) ======
__global__ __launch_bounds__(256)
void k_gemm2(const float* __restrict__ h1, const float* __restrict__ Ws,
             const float* __restrict__ Wd, const float* __restrict__ Wr,
             float* __restrict__ fs2, float* __restrict__ fd2,
             float* __restrict__ res, int n){
  __shared__ float hs[16][129];
  __shared__ float w[3][128][16];
  int tid = threadIdx.x;
  for (int i = tid; i < 2048; i += 256){
    int k = i >> 4, j = i & 15;
    w[0][k][j] = Ws[i]; w[1][k][j] = Wd[i]; w[2][k][j] = Wr[i];
  }
  int node0 = blockIdx.x * 16;
  for (int i = tid; i < 2048; i += 256){
    int r = i >> 7, c = i & 127;
    int nd = node0 + r;
    hs[r][c] = (nd < n) ? h1[(size_t)nd*128 + c] : 0.f;
  }
  __syncthreads();
  int j = tid & 15, ni = tid >> 4;
  float as = 0.f, ad = 0.f, ar = 0.f;
  for (int k = 0; k < 128; ++k){
    float hv = hs[ni][k];
    as = fmaf(hv, w[0][k][j], as);
    ad = fmaf(hv, w[1][k][j], ad);
    ar = fmaf(hv, w[2][k][j], ar);
  }
  int nd = node0 + ni;
  if (nd < n){
    fs2[(size_t)nd*16 + j] = as;
    fd2[(size_t)nd*16 + j] = ad;
    res[(size_t)nd*16 + j] = ar;
  }
}

// ============ Layer 2 fused: per-node online softmax + residual -> d_out =====
__global__ __launch_bounds__(256)
void k_l2_node(const float* __restrict__ fs2, const float* __restrict__ fd2,
               const float* __restrict__ resd, const int* __restrict__ off,
               const int* __restrict__ csr, const float* __restrict__ a2,
               float* __restrict__ outp, int n){
  int wid  = (int)((blockIdx.x*256u + threadIdx.x) >> 6);
  int lane = threadIdx.x & 63;
  if (wid >= n) return;
  int d = wid;
  int g = lane >> 4, j = lane & 15;
  int e0 = off[d], e1 = off[d+1];
  float fdv = fd2[(size_t)d*16 + j];
  float aw  = a2[j];
  float m = FNEG_MAX, den = 0.f, acc = 0.f;
  for (int i = e0 + g; i < e1; i += 4){
    int s = csr[i];
    float v = fs2[(size_t)s*16 + j];
    float x = v + fdv; x = x > 0.f ? x : NEG*x;
    float p = x * aw;
    #pragma unroll
    for (int o = 8; o >= 1; o >>= 1) p += __shfl_xor(p, o, 64);
    float nm = fmaxf(m, p);
    float sc = __expf(m - nm);
    float w  = __expf(p - nm);
    den = den*sc + w;
    acc = acc*sc + w*v;
    m = nm;
  }
  // merge the 4 groups' (m, den, acc): butterfly xor 16 then 32
  #pragma unroll
  for (int o = 16; o <= 32; o <<= 1){
    float om   = __shfl_xor(m,   o, 64);
    float oden = __shfl_xor(den, o, 64);
    float oacc = __shfl_xor(acc, o, 64);
    float nm = fmaxf(m, om);
    float s1 = __expf(m - nm);
    float s2 = __expf(om - nm);
    den = den*s1 + oden*s2;
    acc = acc*s1 + oacc*s2;
    m = nm;
  }
  if (g == 0){
    float inv = (den > 0.f) ? 1.f/den : 0.f;
    outp[(size_t)d*16 + j] = acc*inv + resd[(size_t)d*16 + j];
  }
}

extern "C" void kernel_launch(void* const* d_in, const int* in_sizes, int n_in,
                              void* d_out, int out_size, void* d_ws, size_t ws_size,
                              hipStream_t stream) {
  const float* h    = (const float*)d_in[0];
  const int*   src  = (const int*)  d_in[1];
  const int*   dst  = (const int*)  d_in[2];
  const float* W1s  = (const float*)d_in[3];
  const float* W1d  = (const float*)d_in[4];
  const float* a1   = (const float*)d_in[5];
  const float* W2s  = (const float*)d_in[6];
  const float* W2d  = (const float*)d_in[7];
  const float* a2   = (const float*)d_in[8];
  const float* Wres = (const float*)d_in[9];
  float* out = (float*)d_out;

  const int n  = in_sizes[0] / 128;   // 50000
  const int ne = in_sizes[1];         // 1600000

  // ---- workspace layout ----
  float* ws  = (float*)d_ws;
  float* fs1 = ws;                         // n*128
  float* fd1 = fs1 + (size_t)n*128;        // n*128 (becomes h1 in k_l1_node)
  float* fs2 = fd1 + (size_t)n*128;        // n*16
  float* fd2 = fs2 + (size_t)n*16;         // n*16
  float* res = fd2 + (size_t)n*16;         // n*16
  int* deg     = (int*)(res + (size_t)n*16); // n
  int* off     = deg + n;                    // n+1
  int* cur     = off + (n+1);                // n
  int* bsum    = cur + n;                    // scan block sums (<= 128)
  int* csr_src = bsum + 128;                 // ne

  const int nblk = (n + SCB - 1) / SCB;

  // ---- CSR build ----
  hipMemsetAsync(deg, 0, (size_t)n*4, stream);
  hipMemsetAsync(cur, 0, (size_t)n*4, stream);
  k_count  <<<(ne + 255)/256, 256, 0, stream>>>(dst, deg, ne);
  k_scan1  <<<nblk, SCB, 0, stream>>>(deg, off, bsum, n);
  k_scan2  <<<1, 64, 0, stream>>>(bsum, nblk);
  k_scan3  <<<nblk, SCB, 0, stream>>>(off, bsum, n, ne);
  k_scatter<<<(ne + 255)/256, 256, 0, stream>>>(src, dst, off, cur, csr_src, ne);

  // ---- layer 1 ----
  k_gemm1  <<<(n + GM1 - 1)/GM1, 256, 0, stream>>>(h, W1s, W1d, fs1, fd1, n);
  k_l1_node<<<(n + 3)/4, 256, 0, stream>>>(fs1, fd1, off, csr_src, a1, fd1, n);

  // ---- layer 2 (writes d_out directly) ----
  k_gemm2  <<<(n + 15)/16, 256, 0, stream>>>(fd1, W2s, W2d, Wres, fs2, fd2, res, n);
  k_l2_node<<<(n + 3)/4, 256, 0, stream>>>(fs2, fd2, res, off, csr_src, a2, out, n);
}

// Round 12
// 384.449 us; speedup vs baseline: 5.4365x; 1.0826x over previous
//
#include <hip/hip_runtime.h>
#include <hip/hip_bf16.h>

#define NEG 0.2f
#define FNEG_MAX -3.402823466e38f

// round-to-nearest-even fp32 -> bf16 (as u16)
__device__ __forceinline__ unsigned short f2bf(float f){
  unsigned u = __float_as_uint(f);
  return (unsigned short)((u + 0x7fffu + ((u >> 16) & 1u)) >> 16);
}
__device__ __forceinline__ unsigned pk2bf(float a, float b){
  return (unsigned)f2bf(a) | ((unsigned)f2bf(b) << 16);
}
__device__ __forceinline__ float bflo(unsigned u){ return __uint_as_float(u << 16); }
__device__ __forceinline__ float bfhi(unsigned u){ return __uint_as_float(u & 0xffff0000u); }

// ============ CSR build ============
__global__ __launch_bounds__(256)
void k_count(const int* __restrict__ dst, int* __restrict__ deg, int ne){
  int e = blockIdx.x*256 + threadIdx.x;
  if (e < ne) atomicAdd(&deg[dst[e]], 1);
}

#define SCB 512
__global__ __launch_bounds__(SCB)
void k_scan1(const int* __restrict__ deg, int* __restrict__ off,
             int* __restrict__ bsum, int n){
  __shared__ int lds[SCB];
  int t = threadIdx.x, i = blockIdx.x*SCB + t;
  int x = (i < n) ? deg[i] : 0;
  lds[t] = x; __syncthreads();
  for (int s = 1; s < SCB; s <<= 1){
    int v = (t >= s) ? lds[t-s] : 0;
    __syncthreads();
    lds[t] += v;
    __syncthreads();
  }
  if (i < n) off[i] = lds[t] - x;            // exclusive
  if (t == SCB-1) bsum[blockIdx.x] = lds[t]; // block total
}

__global__ void k_scan2(int* __restrict__ bsum, int nblk){
  if (threadIdx.x == 0 && blockIdx.x == 0){
    int acc = 0;
    for (int b = 0; b < nblk; ++b){ int v = bsum[b]; bsum[b] = acc; acc += v; }
  }
}

__global__ __launch_bounds__(SCB)
void k_scan3(int* __restrict__ off, const int* __restrict__ bsum, int n, int ne){
  int i = blockIdx.x*SCB + threadIdx.x;
  if (i < n) off[i] += bsum[blockIdx.x];
  if (i == 0) off[n] = ne;
}

__global__ __launch_bounds__(256)
void k_scatter(const int* __restrict__ src, const int* __restrict__ dst,
               const int* __restrict__ off, int* __restrict__ cur,
               int* __restrict__ csr_src, int ne){
  int e = blockIdx.x*256 + threadIdx.x;
  if (e >= ne) return;
  int d = dst[e];
  int pos = off[d] + atomicAdd(&cur[d], 1);
  csr_src[pos] = src[e];
}

// ============ Layer 1 GEMM: fs(bf16) = h@Ws, fd(fp32) = h@Wd ================
#define GM1 32
__global__ __launch_bounds__(256)
void k_gemm1(const float* __restrict__ h, const float* __restrict__ Ws,
             const float* __restrict__ Wd, unsigned* __restrict__ fs,
             float* __restrict__ fd, int n){
  __shared__ float ht[128][36];
  int tid = threadIdx.x;
  int node0 = blockIdx.x * GM1;
  for (int i = tid; i < GM1*128; i += 256){
    int r = i >> 7, c = i & 127;
    int nd = node0 + r;
    ht[c][r] = (nd < n) ? h[(size_t)nd*128 + c] : 0.f;
  }
  __syncthreads();
  int cg  = tid & 31;          // 4-col group: cols 4*cg..4*cg+3
  int mat = (tid >> 5) & 1;    // 0: Ws -> fs (bf16), 1: Wd -> fd (fp32)
  int q   = tid >> 6;          // node quarter: nodes q*8..q*8+7
  const float4* W4 = (const float4*)(mat ? Wd : Ws);
  float acc[8][4];
  #pragma unroll
  for (int j = 0; j < 8; ++j){ acc[j][0]=0.f; acc[j][1]=0.f; acc[j][2]=0.f; acc[j][3]=0.f; }
  for (int k = 0; k < 128; ++k){
    float4 w = W4[k*32 + cg];
    const float4* hp4 = (const float4*)&ht[k][q*8];
    float4 ha = hp4[0], hb = hp4[1];
    float hv[8] = {ha.x, ha.y, ha.z, ha.w, hb.x, hb.y, hb.z, hb.w};
    #pragma unroll
    for (int j = 0; j < 8; ++j){
      acc[j][0] = fmaf(hv[j], w.x, acc[j][0]);
      acc[j][1] = fmaf(hv[j], w.y, acc[j][1]);
      acc[j][2] = fmaf(hv[j], w.z, acc[j][2]);
      acc[j][3] = fmaf(hv[j], w.w, acc[j][3]);
    }
  }
  #pragma unroll
  for (int j = 0; j < 8; ++j){
    int nd = node0 + q*8 + j;
    if (nd < n){
      if (mat == 0){
        uint2 o; o.x = pk2bf(acc[j][0], acc[j][1]); o.y = pk2bf(acc[j][2], acc[j][3]);
        ((uint2*)fs)[(size_t)nd*32 + cg] = o;       // row = 64 uints = 32 uint2
      } else {
        float4 o; o.x=acc[j][0]; o.y=acc[j][1]; o.z=acc[j][2]; o.w=acc[j][3];
        ((float4*)fd)[(size_t)nd*32 + cg] = o;
      }
    }
  }
}

// ============ Layer 1 fused: per-node online-softmax aggregate + ELU =========
// 32 lanes per edge, 4 dims per lane, gathers are bf16x4 (8 B/lane, uint2).
// Wave = 2 edges (half-waves); 4-step butterfly in 16-lane head groups;
// defer-max rescale; validity masks; halves merged at the end.
// NOTE: `fdv_` and `out` alias (fd1 reused as h1 output): wave-private rows.
#define THR1 10.f
__global__ __launch_bounds__(256)
void k_l1_node(const unsigned* __restrict__ fs, const float* fdv_,
               const int* __restrict__ off, const int* __restrict__ csr,
               const float* __restrict__ a1, float* out, int n){
  int wid  = (int)((blockIdx.x*256u + threadIdx.x) >> 6);
  int lane = threadIdx.x & 63;
  if (wid >= n) return;
  int d  = wid;
  int hh = lane >> 5;       // which edge of the pair
  int lp = lane & 31;       // dims 4lp..4lp+3 of the edge row
  int e0 = off[d], e1 = off[d+1];
  int deg = e1 - e0;
  const uint2* fs2v = (const uint2*)fs;     // row = 32 uint2
  float4 fdv = ((const float4*)fdv_)[(size_t)d*32 + lp];
  float4 aw  = ((const float4*)a1)[lp];
  float m = FNEG_MAX, den = 0.f;
  float4 acc = make_float4(0.f, 0.f, 0.f, 0.f);

  int nt = (deg + 3) & ~3;   // multiple of 4 edges (2 iters of 2)
  for (int k = 0; k < nt; k += 4){
    int eiA = e0 + k + hh;
    int eiB = eiA + 2;
    bool vA = eiA < e1, vB = eiB < e1;
    int sA = csr[vA ? eiA : e0];
    int sB = csr[vB ? eiB : e0];
    uint2 uA = fs2v[(size_t)sA*32 + lp];
    uint2 uB = fs2v[(size_t)sB*32 + lp];
    float xA0 = bflo(uA.x), xA1 = bfhi(uA.x), xA2 = bflo(uA.y), xA3 = bfhi(uA.y);
    float xB0 = bflo(uB.x), xB1 = bfhi(uB.x), xB2 = bflo(uB.y), xB3 = bfhi(uB.y);
    float pA, pB;
    {
      float t0 = xA0 + fdv.x, t1 = xA1 + fdv.y;
      float t2 = xA2 + fdv.z, t3 = xA3 + fdv.w;
      t0 = fmaxf(t0, NEG*t0); t1 = fmaxf(t1, NEG*t1);
      t2 = fmaxf(t2, NEG*t2); t3 = fmaxf(t3, NEG*t3);
      pA = fmaf(t0, aw.x, fmaf(t1, aw.y, fmaf(t2, aw.z, t3*aw.w)));
    }
    {
      float t0 = xB0 + fdv.x, t1 = xB1 + fdv.y;
      float t2 = xB2 + fdv.z, t3 = xB3 + fdv.w;
      t0 = fmaxf(t0, NEG*t0); t1 = fmaxf(t1, NEG*t1);
      t2 = fmaxf(t2, NEG*t2); t3 = fmaxf(t3, NEG*t3);
      pB = fmaf(t0, aw.x, fmaf(t1, aw.y, fmaf(t2, aw.z, t3*aw.w)));
    }
    // 4-step butterfly within 16-lane head groups; both edges in parallel
    #pragma unroll
    for (int o = 8; o >= 1; o >>= 1){
      pA += __shfl_xor(pA, o, 64);
      pB += __shfl_xor(pB, o, 64);
    }
    pA = vA ? pA : FNEG_MAX;
    pB = vB ? pB : FNEG_MAX;
    float pmax = fmaxf(pA, pB);
    if (__any(pmax > m + THR1)){         // rare rescale
      float nm = fmaxf(m, pmax);
      float sc = __expf(m - nm);         // m==FNEG_MAX -> exp underflows to 0
      den *= sc;
      acc.x *= sc; acc.y *= sc; acc.z *= sc; acc.w *= sc;
      m = nm;
    }
    float wA = vA ? __expf(pA - m) : 0.f;
    float wB = vB ? __expf(pB - m) : 0.f;
    den += wA + wB;
    acc.x = fmaf(wA, xA0, fmaf(wB, xB0, acc.x));
    acc.y = fmaf(wA, xA1, fmaf(wB, xB1, acc.y));
    acc.z = fmaf(wA, xA2, fmaf(wB, xB2, acc.z));
    acc.w = fmaf(wA, xA3, fmaf(wB, xB3, acc.w));
  }

  // merge the two half-wave partials
  float om   = __shfl_xor(m,   32, 64);
  float oden = __shfl_xor(den, 32, 64);
  float4 oacc;
  oacc.x = __shfl_xor(acc.x, 32, 64);
  oacc.y = __shfl_xor(acc.y, 32, 64);
  oacc.z = __shfl_xor(acc.z, 32, 64);
  oacc.w = __shfl_xor(acc.w, 32, 64);
  float nm = fmaxf(m, om);
  float s1 = __expf(m - nm), s2 = __expf(om - nm);
  den = den*s1 + oden*s2;
  float4 r;
  r.x = acc.x*s1 + oacc.x*s2;
  r.y = acc.y*s1 + oacc.y*s2;
  r.z = acc.z*s1 + oacc.z*s2;
  r.w = acc.w*s1 + oacc.w*s2;
  float inv = (den > 0.f) ? 1.f/den : 0.f;
  r.x *= inv; r.y *= inv; r.z *= inv; r.w *= inv;
  r.x = r.x > 0.f ? r.x : __expf(r.x) - 1.f;   // ELU fused
  r.y = r.y > 0.f ? r.y : __expf(r.y) - 1.f;
  r.z = r.z > 0.f ? r.z : __expf(r.z) - 1.f;
  r.w = r.w > 0.f ? r.w : __expf(r.w) - 1.f;
  if (hh == 0) ((float4*)out)[(size_t)d*32 + lp] = r;
}

// ============ Layer 2 GEMM: fs2(bf16)/fd2/res = h1 @ {W2s,W2d,Wr} ===========
__global__ __launch_bounds__(256)
void k_gemm2(const float* __restrict__ h1, const float* __restrict__ Ws,
             const float* __restrict__ Wd, const float* __restrict__ Wr,
             unsigned short* __restrict__ fs2, float* __restrict__ fd2,
             float* __restrict__ res, int n){
  __shared__ float hs[16][129];
  __shared__ float w[3][128][16];
  int tid = threadIdx.x;
  for (int i = tid; i < 2048; i += 256){
    int k = i >> 4, j = i & 15;
    w[0][k][j] = Ws[i]; w[1][k][j] = Wd[i]; w[2][k][j] = Wr[i];
  }
  int node0 = blockIdx.x * 16;
  for (int i = tid; i < 2048; i += 256){
    int r = i >> 7, c = i & 127;
    int nd = node0 + r;
    hs[r][c] = (nd < n) ? h1[(size_t)nd*128 + c] : 0.f;
  }
  __syncthreads();
  int j = tid & 15, ni = tid >> 4;
  float as = 0.f, ad = 0.f, ar = 0.f;
  for (int k = 0; k < 128; ++k){
    float hv = hs[ni][k];
    as = fmaf(hv, w[0][k][j], as);
    ad = fmaf(hv, w[1][k][j], ad);
    ar = fmaf(hv, w[2][k][j], ar);
  }
  int nd = node0 + ni;
  if (nd < n){
    fs2[(size_t)nd*16 + j] = f2bf(as);
    fd2[(size_t)nd*16 + j] = ad;
    res[(size_t)nd*16 + j] = ar;
  }
}

// ============ Layer 2 fused: per-node online softmax + residual -> d_out =====
__global__ __launch_bounds__(256)
void k_l2_node(const unsigned short* __restrict__ fs2, const float* __restrict__ fd2,
               const float* __restrict__ resd, const int* __restrict__ off,
               const int* __restrict__ csr, const float* __restrict__ a2,
               float* __restrict__ outp, int n){
  int wid  = (int)((blockIdx.x*256u + threadIdx.x) >> 6);
  int lane = threadIdx.x & 63;
  if (wid >= n) return;
  int d = wid;
  int g = lane >> 4, j = lane & 15;
  int e0 = off[d], e1 = off[d+1];
  float fdv = fd2[(size_t)d*16 + j];
  float aw  = a2[j];
  float m = FNEG_MAX, den = 0.f, acc = 0.f;
  for (int i = e0 + g; i < e1; i += 4){
    int s = csr[i];
    float v = __uint_as_float((unsigned)fs2[(size_t)s*16 + j] << 16);
    float x = v + fdv; x = x > 0.f ? x : NEG*x;
    float p = x * aw;
    #pragma unroll
    for (int o = 8; o >= 1; o >>= 1) p += __shfl_xor(p, o, 64);
    float nm = fmaxf(m, p);
    float sc = __expf(m - nm);
    float w  = __expf(p - nm);
    den = den*sc + w;
    acc = acc*sc + w*v;
    m = nm;
  }
  // merge the 4 groups' (m, den, acc): butterfly xor 16 then 32
  #pragma unroll
  for (int o = 16; o <= 32; o <<= 1){
    float om   = __shfl_xor(m,   o, 64);
    float oden = __shfl_xor(den, o, 64);
    float oacc = __shfl_xor(acc, o, 64);
    float nm = fmaxf(m, om);
    float s1 = __expf(m - nm);
    float s2 = __expf(om - nm);
    den = den*s1 + oden*s2;
    acc = acc*s1 + oacc*s2;
    m = nm;
  }
  if (g == 0){
    float inv = (den > 0.f) ? 1.f/den : 0.f;
    outp[(size_t)d*16 + j] = acc*inv + resd[(size_t)d*16 + j];
  }
}

extern "C" void kernel_launch(void* const* d_in, const int* in_sizes, int n_in,
                              void* d_out, int out_size, void* d_ws, size_t ws_size,
                              hipStream_t stream) {
  const float* h    = (const float*)d_in[0];
  const int*   src  = (const int*)  d_in[1];
  const int*   dst  = (const int*)  d_in[2];
  const float* W1s  = (const float*)d_in[3];
  const float* W1d  = (const float*)d_in[4];
  const float* a1   = (const float*)d_in[5];
  const float* W2s  = (const float*)d_in[6];
  const float* W2d  = (const float*)d_in[7];
  const float* a2   = (const float*)d_in[8];
  const float* Wres = (const float*)d_in[9];
  float* out = (float*)d_out;

  const int n  = in_sizes[0] / 128;   // 50000
  const int ne = in_sizes[1];         // 1600000

  // ---- workspace layout (region sizes unchanged; bf16 uses first half) ----
  float* ws  = (float*)d_ws;
  float* fs1 = ws;                         // n*128 region (bf16 uses n*64 uints)
  float* fd1 = fs1 + (size_t)n*128;        // n*128 (becomes h1 in k_l1_node)
  float* fs2 = fd1 + (size_t)n*128;        // n*16 region (bf16 uses n*8 floats)
  float* fd2 = fs2 + (size_t)n*16;         // n*16
  float* res = fd2 + (size_t)n*16;         // n*16
  int* deg     = (int*)(res + (size_t)n*16); // n
  int* off     = deg + n;                    // n+1
  int* cur     = off + (n+1);                // n
  int* bsum    = cur + n;                    // scan block sums (<= 128)
  int* csr_src = bsum + 128;                 // ne

  const int nblk = (n + SCB - 1) / SCB;

  // ---- CSR build ----
  hipMemsetAsync(deg, 0, (size_t)n*4, stream);
  hipMemsetAsync(cur, 0, (size_t)n*4, stream);
  k_count  <<<(ne + 255)/256, 256, 0, stream>>>(dst, deg, ne);
  k_scan1  <<<nblk, SCB, 0, stream>>>(deg, off, bsum, n);
  k_scan2  <<<1, 64, 0, stream>>>(bsum, nblk);
  k_scan3  <<<nblk, SCB, 0, stream>>>(off, bsum, n, ne);
  k_scatter<<<(ne + 255)/256, 256, 0, stream>>>(src, dst, off, cur, csr_src, ne);

  // ---- layer 1 ----
  k_gemm1  <<<(n + GM1 - 1)/GM1, 256, 0, stream>>>(h, W1s, W1d, (unsigned*)fs1, fd1, n);
  k_l1_node<<<(n + 3)/4, 256, 0, stream>>>((const unsigned*)fs1, fd1, off, csr_src, a1, fd1, n);

  // ---- layer 2 (writes d_out directly) ----
  k_gemm2  <<<(n + 15)/16, 256, 0, stream>>>(fd1, W2s, W2d, Wres, (unsigned short*)fs2, fd2, res, n);
  k_l2_node<<<(n + 3)/4, 256, 0, stream>>>((const unsigned short*)fs2, fd2, res, off, csr_src, a2, out, n);
}

// Round 13
// 374.443 us; speedup vs baseline: 5.5817x; 1.0267x over previous
//
#include <hip/hip_runtime.h>
#include <hip/hip_bf16.h>

#define NEG 0.2f
#define FNEG_MAX -3.402823466e38f

// round-to-nearest-even fp32 -> bf16 (as u16)
__device__ __forceinline__ unsigned short f2bf(float f){
  unsigned u = __float_as_uint(f);
  return (unsigned short)((u + 0x7fffu + ((u >> 16) & 1u)) >> 16);
}
__device__ __forceinline__ unsigned pk2bf(float a, float b){
  return (unsigned)f2bf(a) | ((unsigned)f2bf(b) << 16);
}
__device__ __forceinline__ float bflo(unsigned u){ return __uint_as_float(u << 16); }
__device__ __forceinline__ float bfhi(unsigned u){ return __uint_as_float(u & 0xffff0000u); }

// ============ CSR build ============
__global__ __launch_bounds__(256)
void k_count(const int* __restrict__ dst, int* __restrict__ deg, int ne){
  int e = blockIdx.x*256 + threadIdx.x;
  if (e < ne) atomicAdd(&deg[dst[e]], 1);
}

#define SCB 512
__global__ __launch_bounds__(SCB)
void k_scan1(const int* __restrict__ deg, int* __restrict__ off,
             int* __restrict__ bsum, int n){
  __shared__ int lds[SCB];
  int t = threadIdx.x, i = blockIdx.x*SCB + t;
  int x = (i < n) ? deg[i] : 0;
  lds[t] = x; __syncthreads();
  for (int s = 1; s < SCB; s <<= 1){
    int v = (t >= s) ? lds[t-s] : 0;
    __syncthreads();
    lds[t] += v;
    __syncthreads();
  }
  if (i < n) off[i] = lds[t] - x;            // exclusive
  if (t == SCB-1) bsum[blockIdx.x] = lds[t]; // block total
}

__global__ void k_scan2(int* __restrict__ bsum, int nblk){
  if (threadIdx.x == 0 && blockIdx.x == 0){
    int acc = 0;
    for (int b = 0; b < nblk; ++b){ int v = bsum[b]; bsum[b] = acc; acc += v; }
  }
}

__global__ __launch_bounds__(SCB)
void k_scan3(int* __restrict__ off, const int* __restrict__ bsum, int n, int ne){
  int i = blockIdx.x*SCB + threadIdx.x;
  if (i < n) off[i] += bsum[blockIdx.x];
  if (i == 0) off[n] = ne;
}

__global__ __launch_bounds__(256)
void k_scatter(const int* __restrict__ src, const int* __restrict__ dst,
               const int* __restrict__ off, int* __restrict__ cur,
               int* __restrict__ csr_src, int ne){
  int e = blockIdx.x*256 + threadIdx.x;
  if (e >= ne) return;
  int d = dst[e];
  int pos = off[d] + atomicAdd(&cur[d], 1);
  csr_src[pos] = src[e];
}

// ============ Layer 1 GEMM: fs(bf16) = h@Ws, fd(fp32) = h@Wd ================
#define GM1 32
__global__ __launch_bounds__(256)
void k_gemm1(const float* __restrict__ h, const float* __restrict__ Ws,
             const float* __restrict__ Wd, unsigned* __restrict__ fs,
             float* __restrict__ fd, int n){
  __shared__ float ht[128][36];
  int tid = threadIdx.x;
  int node0 = blockIdx.x * GM1;
  for (int i = tid; i < GM1*128; i += 256){
    int r = i >> 7, c = i & 127;
    int nd = node0 + r;
    ht[c][r] = (nd < n) ? h[(size_t)nd*128 + c] : 0.f;
  }
  __syncthreads();
  int cg  = tid & 31;          // 4-col group: cols 4*cg..4*cg+3
  int mat = (tid >> 5) & 1;    // 0: Ws -> fs (bf16), 1: Wd -> fd (fp32)
  int q   = tid >> 6;          // node quarter: nodes q*8..q*8+7
  const float4* W4 = (const float4*)(mat ? Wd : Ws);
  float acc[8][4];
  #pragma unroll
  for (int j = 0; j < 8; ++j){ acc[j][0]=0.f; acc[j][1]=0.f; acc[j][2]=0.f; acc[j][3]=0.f; }
  for (int k = 0; k < 128; ++k){
    float4 w = W4[k*32 + cg];
    const float4* hp4 = (const float4*)&ht[k][q*8];
    float4 ha = hp4[0], hb = hp4[1];
    float hv[8] = {ha.x, ha.y, ha.z, ha.w, hb.x, hb.y, hb.z, hb.w};
    #pragma unroll
    for (int j = 0; j < 8; ++j){
      acc[j][0] = fmaf(hv[j], w.x, acc[j][0]);
      acc[j][1] = fmaf(hv[j], w.y, acc[j][1]);
      acc[j][2] = fmaf(hv[j], w.z, acc[j][2]);
      acc[j][3] = fmaf(hv[j], w.w, acc[j][3]);
    }
  }
  #pragma unroll
  for (int j = 0; j < 8; ++j){
    int nd = node0 + q*8 + j;
    if (nd < n){
      if (mat == 0){
        uint2 o; o.x = pk2bf(acc[j][0], acc[j][1]); o.y = pk2bf(acc[j][2], acc[j][3]);
        ((uint2*)fs)[(size_t)nd*32 + cg] = o;       // row = 64 uints = 32 uint2
      } else {
        float4 o; o.x=acc[j][0]; o.y=acc[j][1]; o.z=acc[j][2]; o.w=acc[j][3];
        ((float4*)fd)[(size_t)nd*32 + cg] = o;
      }
    }
  }
}

// ============ Layer 1 fused: per-node online-softmax aggregate + ELU =========
// 32 lanes per edge, 4 dims per lane, gathers are bf16x4 (8 B/lane, uint2).
// Wave = 2 edges (half-waves); 4-step butterfly in 16-lane head groups;
// defer-max rescale; validity masks; halves merged at the end.
// NOTE: `fdv_` and `out` alias (fd1 reused as h1 output): wave-private rows.
#define THR1 10.f
__global__ __launch_bounds__(256)
void k_l1_node(const unsigned* __restrict__ fs, const float* fdv_,
               const int* __restrict__ off, const int* __restrict__ csr,
               const float* __restrict__ a1, float* out, int n){
  int wid  = (int)((blockIdx.x*256u + threadIdx.x) >> 6);
  int lane = threadIdx.x & 63;
  if (wid >= n) return;
  int d  = wid;
  int hh = lane >> 5;       // which edge of the pair
  int lp = lane & 31;       // dims 4lp..4lp+3 of the edge row
  int e0 = off[d], e1 = off[d+1];
  int deg = e1 - e0;
  const uint2* fs2v = (const uint2*)fs;     // row = 32 uint2
  float4 fdv = ((const float4*)fdv_)[(size_t)d*32 + lp];
  float4 aw  = ((const float4*)a1)[lp];
  float m = FNEG_MAX, den = 0.f;
  float4 acc = make_float4(0.f, 0.f, 0.f, 0.f);

  int nt = (deg + 3) & ~3;   // multiple of 4 edges (2 iters of 2)
  for (int k = 0; k < nt; k += 4){
    int eiA = e0 + k + hh;
    int eiB = eiA + 2;
    bool vA = eiA < e1, vB = eiB < e1;
    int sA = csr[vA ? eiA : e0];
    int sB = csr[vB ? eiB : e0];
    uint2 uA = fs2v[(size_t)sA*32 + lp];
    uint2 uB = fs2v[(size_t)sB*32 + lp];
    float xA0 = bflo(uA.x), xA1 = bfhi(uA.x), xA2 = bflo(uA.y), xA3 = bfhi(uA.y);
    float xB0 = bflo(uB.x), xB1 = bfhi(uB.x), xB2 = bflo(uB.y), xB3 = bfhi(uB.y);
    float pA, pB;
    {
      float t0 = xA0 + fdv.x, t1 = xA1 + fdv.y;
      float t2 = xA2 + fdv.z, t3 = xA3 + fdv.w;
      t0 = fmaxf(t0, NEG*t0); t1 = fmaxf(t1, NEG*t1);
      t2 = fmaxf(t2, NEG*t2); t3 = fmaxf(t3, NEG*t3);
      pA = fmaf(t0, aw.x, fmaf(t1, aw.y, fmaf(t2, aw.z, t3*aw.w)));
    }
    {
      float t0 = xB0 + fdv.x, t1 = xB1 + fdv.y;
      float t2 = xB2 + fdv.z, t3 = xB3 + fdv.w;
      t0 = fmaxf(t0, NEG*t0); t1 = fmaxf(t1, NEG*t1);
      t2 = fmaxf(t2, NEG*t2); t3 = fmaxf(t3, NEG*t3);
      pB = fmaf(t0, aw.x, fmaf(t1, aw.y, fmaf(t2, aw.z, t3*aw.w)));
    }
    // 4-step butterfly within 16-lane head groups; both edges in parallel
    #pragma unroll
    for (int o = 8; o >= 1; o >>= 1){
      pA += __shfl_xor(pA, o, 64);
      pB += __shfl_xor(pB, o, 64);
    }
    pA = vA ? pA : FNEG_MAX;
    pB = vB ? pB : FNEG_MAX;
    float pmax = fmaxf(pA, pB);
    if (__any(pmax > m + THR1)){         // rare rescale
      float nm = fmaxf(m, pmax);
      float sc = __expf(m - nm);         // m==FNEG_MAX -> exp underflows to 0
      den *= sc;
      acc.x *= sc; acc.y *= sc; acc.z *= sc; acc.w *= sc;
      m = nm;
    }
    float wA = vA ? __expf(pA - m) : 0.f;
    float wB = vB ? __expf(pB - m) : 0.f;
    den += wA + wB;
    acc.x = fmaf(wA, xA0, fmaf(wB, xB0, acc.x));
    acc.y = fmaf(wA, xA1, fmaf(wB, xB1, acc.y));
    acc.z = fmaf(wA, xA2, fmaf(wB, xB2, acc.z));
    acc.w = fmaf(wA, xA3, fmaf(wB, xB3, acc.w));
  }

  // merge the two half-wave partials
  float om   = __shfl_xor(m,   32, 64);
  float oden = __shfl_xor(den, 32, 64);
  float4 oacc;
  oacc.x = __shfl_xor(acc.x, 32, 64);
  oacc.y = __shfl_xor(acc.y, 32, 64);
  oacc.z = __shfl_xor(acc.z, 32, 64);
  oacc.w = __shfl_xor(acc.w, 32, 64);
  float nm = fmaxf(m, om);
  float s1 = __expf(m - nm), s2 = __expf(om - nm);
  den = den*s1 + oden*s2;
  float4 r;
  r.x = acc.x*s1 + oacc.x*s2;
  r.y = acc.y*s1 + oacc.y*s2;
  r.z = acc.z*s1 + oacc.z*s2;
  r.w = acc.w*s1 + oacc.w*s2;
  float inv = (den > 0.f) ? 1.f/den : 0.f;
  r.x *= inv; r.y *= inv; r.z *= inv; r.w *= inv;
  r.x = r.x > 0.f ? r.x : __expf(r.x) - 1.f;   // ELU fused
  r.y = r.y > 0.f ? r.y : __expf(r.y) - 1.f;
  r.z = r.z > 0.f ? r.z : __expf(r.z) - 1.f;
  r.w = r.w > 0.f ? r.w : __expf(r.w) - 1.f;
  if (hh == 0) ((float4*)out)[(size_t)d*32 + lp] = r;
}

// ============ Layer 2 GEMM: fs2(bf16)/fd2/res = h1 @ {W2s,W2d,Wr} ===========
__global__ __launch_bounds__(256)
void k_gemm2(const float* __restrict__ h1, const float* __restrict__ Ws,
             const float* __restrict__ Wd, const float* __restrict__ Wr,
             unsigned short* __restrict__ fs2, float* __restrict__ fd2,
             float* __restrict__ res, int n){
  __shared__ float hs[16][129];
  __shared__ float w[3][128][16];
  int tid = threadIdx.x;
  for (int i = tid; i < 2048; i += 256){
    int k = i >> 4, j = i & 15;
    w[0][k][j] = Ws[i]; w[1][k][j] = Wd[i]; w[2][k][j] = Wr[i];
  }
  int node0 = blockIdx.x * 16;
  for (int i = tid; i < 2048; i += 256){
    int r = i >> 7, c = i & 127;
    int nd = node0 + r;
    hs[r][c] = (nd < n) ? h1[(size_t)nd*128 + c] : 0.f;
  }
  __syncthreads();
  int j = tid & 15, ni = tid >> 4;
  float as = 0.f, ad = 0.f, ar = 0.f;
  for (int k = 0; k < 128; ++k){
    float hv = hs[ni][k];
    as = fmaf(hv, w[0][k][j], as);
    ad = fmaf(hv, w[1][k][j], ad);
    ar = fmaf(hv, w[2][k][j], ar);
  }
  int nd = node0 + ni;
  if (nd < n){
    fs2[(size_t)nd*16 + j] = f2bf(as);
    fd2[(size_t)nd*16 + j] = ad;
    res[(size_t)nd*16 + j] = ar;
  }
}

// ============ Layer 2 fused: per-node online softmax + residual -> d_out =====
// 16 lanes per edge (dim j); 4 groups x 2-edge unroll = 8 edges in flight.
// Defer-max rescale; validity masks; uniform trip count ceil(deg/8) across
// the wave (no divergence); 4-group merge at the end.
#define THR2 10.f
__global__ __launch_bounds__(256)
void k_l2_node(const unsigned short* __restrict__ fs2, const float* __restrict__ fd2,
               const float* __restrict__ resd, const int* __restrict__ off,
               const int* __restrict__ csr, const float* __restrict__ a2,
               float* __restrict__ outp, int n){
  int wid  = (int)((blockIdx.x*256u + threadIdx.x) >> 6);
  int lane = threadIdx.x & 63;
  if (wid >= n) return;
  int d = wid;
  int g = lane >> 4, j = lane & 15;
  int e0 = off[d], e1 = off[d+1];
  int deg = e1 - e0;
  float fdv = fd2[(size_t)d*16 + j];
  float aw  = a2[j];
  float m = FNEG_MAX, den = 0.f, acc = 0.f;
  int jmax = (deg + 7) >> 3;           // wave-uniform trip count
  for (int it = 0; it < jmax; ++it){
    int iA = e0 + it*8 + g;
    int iB = iA + 4;
    bool vA = iA < e1, vB = iB < e1;
    int sA = csr[vA ? iA : e0];
    int sB = csr[vB ? iB : e0];
    float xA = __uint_as_float((unsigned)fs2[(size_t)sA*16 + j] << 16);
    float xB = __uint_as_float((unsigned)fs2[(size_t)sB*16 + j] << 16);
    float tA = xA + fdv; tA = fmaxf(tA, NEG*tA);
    float tB = xB + fdv; tB = fmaxf(tB, NEG*tB);
    float pA = tA * aw, pB = tB * aw;
    #pragma unroll
    for (int o = 8; o >= 1; o >>= 1){
      pA += __shfl_xor(pA, o, 64);
      pB += __shfl_xor(pB, o, 64);
    }
    pA = vA ? pA : FNEG_MAX;
    pB = vB ? pB : FNEG_MAX;
    float pmax = fmaxf(pA, pB);
    if (__any(pmax > m + THR2)){       // rare rescale
      float nm = fmaxf(m, pmax);
      float sc = __expf(m - nm);
      den *= sc; acc *= sc;
      m = nm;
    }
    float wA = vA ? __expf(pA - m) : 0.f;
    float wB = vB ? __expf(pB - m) : 0.f;
    den += wA + wB;
    acc = fmaf(wA, xA, fmaf(wB, xB, acc));
  }
  // merge the 4 groups' (m, den, acc): butterfly xor 16 then 32
  #pragma unroll
  for (int o = 16; o <= 32; o <<= 1){
    float om   = __shfl_xor(m,   o, 64);
    float oden = __shfl_xor(den, o, 64);
    float oacc = __shfl_xor(acc, o, 64);
    float nm = fmaxf(m, om);
    float s1 = __expf(m - nm);
    float s2 = __expf(om - nm);
    den = den*s1 + oden*s2;
    acc = acc*s1 + oacc*s2;
    m = nm;
  }
  if (g == 0){
    float inv = (den > 0.f) ? 1.f/den : 0.f;
    outp[(size_t)d*16 + j] = acc*inv + resd[(size_t)d*16 + j];
  }
}

extern "C" void kernel_launch(void* const* d_in, const int* in_sizes, int n_in,
                              void* d_out, int out_size, void* d_ws, size_t ws_size,
                              hipStream_t stream) {
  const float* h    = (const float*)d_in[0];
  const int*   src  = (const int*)  d_in[1];
  const int*   dst  = (const int*)  d_in[2];
  const float* W1s  = (const float*)d_in[3];
  const float* W1d  = (const float*)d_in[4];
  const float* a1   = (const float*)d_in[5];
  const float* W2s  = (const float*)d_in[6];
  const float* W2d  = (const float*)d_in[7];
  const float* a2   = (const float*)d_in[8];
  const float* Wres = (const float*)d_in[9];
  float* out = (float*)d_out;

  const int n  = in_sizes[0] / 128;   // 50000
  const int ne = in_sizes[1];         // 1600000

  // ---- workspace layout (region sizes unchanged; bf16 uses first half) ----
  float* ws  = (float*)d_ws;
  float* fs1 = ws;                         // n*128 region (bf16 uses n*64 uints)
  float* fd1 = fs1 + (size_t)n*128;        // n*128 (becomes h1 in k_l1_node)
  float* fs2 = fd1 + (size_t)n*128;        // n*16 region (bf16 uses n*8 floats)
  float* fd2 = fs2 + (size_t)n*16;         // n*16
  float* res = fd2 + (size_t)n*16;         // n*16
  int* deg     = (int*)(res + (size_t)n*16); // n
  int* off     = deg + n;                    // n+1
  int* cur     = off + (n+1);                // n
  int* bsum    = cur + n;                    // scan block sums (<= 128)
  int* csr_src = bsum + 128;                 // ne

  const int nblk = (n + SCB - 1) / SCB;

  // ---- CSR build ----
  hipMemsetAsync(deg, 0, (size_t)n*4, stream);
  hipMemsetAsync(cur, 0, (size_t)n*4, stream);
  k_count  <<<(ne + 255)/256, 256, 0, stream>>>(dst, deg, ne);
  k_scan1  <<<nblk, SCB, 0, stream>>>(deg, off, bsum, n);
  k_scan2  <<<1, 64, 0, stream>>>(bsum, nblk);
  k_scan3  <<<nblk, SCB, 0, stream>>>(off, bsum, n, ne);
  k_scatter<<<(ne + 255)/256, 256, 0, stream>>>(src, dst, off, cur, csr_src, ne);

  // ---- layer 1 ----
  k_gemm1  <<<(n + GM1 - 1)/GM1, 256, 0, stream>>>(h, W1s, W1d, (unsigned*)fs1, fd1, n);
  k_l1_node<<<(n + 3)/4, 256, 0, stream>>>((const unsigned*)fs1, fd1, off, csr_src, a1, fd1, n);

  // ---- layer 2 (writes d_out directly) ----
  k_gemm2  <<<(n + 15)/16, 256, 0, stream>>>(fd1, W2s, W2d, Wres, (unsigned short*)fs2, fd2, res, n);
  k_l2_node<<<(n + 3)/4, 256, 0, stream>>>((const unsigned short*)fs2, fd2, res, off, csr_src, a2, out, n);
}